// Round 2
// baseline (7856.602 us; speedup 1.0000x reference)
//
#include <hip/hip_runtime.h>
#include <cstddef>

constexpr int Vv = 32000, Dd = 512, Ss = 1024, Bb = 2, Hh = 8, DHd = 64, FFf = 2048;
constexpr int Tt = Bb * Ss;            // 2048 token rows
constexpr float EPSf = 1e-5f;

// ---------------------------------------------------------------- embed + PE
__global__ __launch_bounds__(256) void embed_pe_k(const int* __restrict__ tok,
                                                  const float* __restrict__ emb,
                                                  float* __restrict__ X,
                                                  float* __restrict__ ENC) {
  int row = blockIdx.x;                 // 0..Tt-1
  int s = row & (Ss - 1);
  int t = tok[row];
  const float* e = emb + (size_t)t * Dd;
  for (int d = threadIdx.x; d < Dd; d += 256) {
    int i = d >> 1;
    float den = expf(-(float)(2 * i) * (9.210340371976184f / 512.0f)); // ln(10000)/D
    float ang = (float)s * den;
    float pe = (d & 1) ? cosf(ang) : sinf(ang);
    float v = e[d] + pe;
    X[(size_t)row * Dd + d] = v;
    ENC[(size_t)row * Dd + d] = v;
  }
}

// ---------------------------------------------------------------- layernorm
__global__ __launch_bounds__(256) void layernorm_k(const float* __restrict__ in,
                                                   const float* __restrict__ g,
                                                   const float* __restrict__ b,
                                                   float* __restrict__ out) {
  int row = blockIdx.x;
  const float* x = in + (size_t)row * Dd;
  int tid = threadIdx.x;
  float v0 = x[tid], v1 = x[tid + 256];
  float s = v0 + v1, ss = v0 * v0 + v1 * v1;
  for (int o = 32; o; o >>= 1) {
    s  += __shfl_down(s, o, 64);
    ss += __shfl_down(ss, o, 64);
  }
  __shared__ float rs[4], rss[4];
  int wid = tid >> 6, lane = tid & 63;
  if (lane == 0) { rs[wid] = s; rss[wid] = ss; }
  __syncthreads();
  __shared__ float mean_s, inv_s;
  if (tid == 0) {
    float a = rs[0] + rs[1] + rs[2] + rs[3];
    float c = rss[0] + rss[1] + rss[2] + rss[3];
    float m = a / Dd;
    float var = c / Dd - m * m;
    mean_s = m;
    inv_s = rsqrtf(var + EPSf);
  }
  __syncthreads();
  float m = mean_s, inv = inv_s;
  out[(size_t)row * Dd + tid]       = (v0 - m) * inv * g[tid]       + b[tid];
  out[(size_t)row * Dd + tid + 256] = (v1 - m) * inv * g[tid + 256] + b[tid + 256];
}

// ------------------------------------------------- repack [H,D,DH]->[D,H*DH]
__global__ __launch_bounds__(256) void repack_k(const float* __restrict__ w,
                                                float* __restrict__ out) {
  int idx = blockIdx.x * 256 + threadIdx.x;   // over Dd*512
  if (idx >= Dd * (Hh * DHd)) return;
  int d = idx >> 9;
  int c = idx & 511;
  int h = c >> 6, e = c & 63;
  out[idx] = w[((size_t)h * Dd + d) * DHd + e];
}

// ---------------------------------------------------------------- tiled GEMM
// C[M,N] = A[M,K] * B[K,N] [+bias] [+resid] [relu]
template <bool RELU>
__global__ __launch_bounds__(256) void gemm_k(const float* __restrict__ A,
                                              const float* __restrict__ Bw,
                                              const float* __restrict__ bias,
                                              const float* __restrict__ resid,
                                              float* __restrict__ C,
                                              int M, int N, int K) {
  __shared__ float As[16][65];   // As[k][m]
  __shared__ float Bs[16][65];   // Bs[k][n]
  int bm = blockIdx.y * 64, bn = blockIdx.x * 64;
  int tid = threadIdx.x;
  int tx = tid & 15, ty = tid >> 4;
  float acc[4][4] = {};
  for (int k0 = 0; k0 < K; k0 += 16) {
    // A tile: 64 rows x 16 cols
#pragma unroll
    for (int i = 0; i < 4; i++) {
      int m = ty + i * 16;
      As[tx][m] = A[(size_t)(bm + m) * K + k0 + tx];
    }
    // B tile: 16 rows x 64 cols (float4 per thread)
    {
      int k = ty, n = tx * 4;
      const float4 bv = *(const float4*)(Bw + (size_t)(k0 + k) * N + bn + n);
      Bs[k][n + 0] = bv.x;
      Bs[k][n + 1] = bv.y;
      Bs[k][n + 2] = bv.z;
      Bs[k][n + 3] = bv.w;
    }
    __syncthreads();
#pragma unroll
    for (int k = 0; k < 16; k++) {
      float a[4], bb[4];
#pragma unroll
      for (int i = 0; i < 4; i++) a[i] = As[k][ty * 4 + i];
#pragma unroll
      for (int j = 0; j < 4; j++) bb[j] = Bs[k][tx * 4 + j];
#pragma unroll
      for (int i = 0; i < 4; i++)
#pragma unroll
        for (int j = 0; j < 4; j++) acc[i][j] += a[i] * bb[j];
    }
    __syncthreads();
  }
#pragma unroll
  for (int i = 0; i < 4; i++) {
    int m = bm + ty * 4 + i;
#pragma unroll
    for (int j = 0; j < 4; j++) {
      int n = bn + tx * 4 + j;
      float v = acc[i][j];
      if (bias)  v += bias[n];
      if (resid) v += resid[(size_t)m * N + n];
      if (RELU)  v = fmaxf(v, 0.0f);
      C[(size_t)m * N + n] = v;
    }
  }
}

// ---------------------------------------------------------------- attention
// One block per (b,h,s). Q/K/V in [B,S,H*DH] f32 layout (head h at col h*64).
__global__ __launch_bounds__(256) void attn_k(const float* __restrict__ Q,
                                              const float* __restrict__ Kb,
                                              const float* __restrict__ Vb,
                                              float* __restrict__ O) {
  int idx = blockIdx.x;
  int s = idx & (Ss - 1);
  int h = (idx >> 10) & (Hh - 1);
  int b = idx >> 13;
  int tid = threadIdx.x;

  __shared__ float qs[DHd];
  __shared__ float p[Ss];
  __shared__ float red[256];

  const float* qp = Q + ((size_t)(b * Ss + s) * Dd + h * DHd);
  if (tid < DHd) qs[tid] = qp[tid];
  __syncthreads();

  const float* kbase = Kb + ((size_t)b * Ss * Dd + h * DHd);
  float lmax = -INFINITY;
  for (int t = tid; t < Ss; t += 256) {
    float sc;
    if (t <= s) {
      const float* kp = kbase + (size_t)t * Dd;
      float d = 0.0f;
#pragma unroll
      for (int e = 0; e < DHd; e++) d += qs[e] * kp[e];
      sc = d * 8.0f;   // faithful: scores MULTIPLIED by sqrt(DH)=8
    } else {
      sc = -INFINITY;
    }
    p[t] = sc;
    lmax = fmaxf(lmax, sc);
  }
  red[tid] = lmax;
  __syncthreads();
  for (int o = 128; o; o >>= 1) {
    if (tid < o) red[tid] = fmaxf(red[tid], red[tid + o]);
    __syncthreads();
  }
  float mx = red[0];
  __syncthreads();

  float lsum = 0.0f;
  for (int t = tid; t < Ss; t += 256) {
    float e = (t <= s) ? __expf(p[t] - mx) : 0.0f;
    p[t] = e;
    lsum += e;
  }
  red[tid] = lsum;
  __syncthreads();
  for (int o = 128; o; o >>= 1) {
    if (tid < o) red[tid] += red[tid + o];
    __syncthreads();
  }
  float denom = red[0];
  __syncthreads();

  // PV: thread (e, j) with e = tid&63, j = tid>>6 handles t-range chunk j
  int e = tid & 63, j = tid >> 6;
  const float* vbase = Vb + ((size_t)b * Ss * Dd + h * DHd);
  float acc = 0.0f;
  int t0 = j * 256;
  int t1 = min(t0 + 256, s + 1);
  for (int t = t0; t < t1; t++) acc += p[t] * vbase[(size_t)t * Dd + e];
  red[tid] = acc;
  __syncthreads();
  if (j == 0) {
    float tot = red[e] + red[e + 64] + red[e + 128] + red[e + 192];
    O[(size_t)(b * Ss + s) * Dd + h * DHd + e] = tot / denom;
  }
}

// ---------------------------------------------------------------- host side
static void gemm_f32(hipStream_t st, const float* A, const float* B, const float* bias,
                     const float* resid, float* C, int M, int N, int K, bool relu) {
  dim3 g(N / 64, M / 64), blk(256);
  if (relu)
    gemm_k<true><<<g, blk, 0, st>>>(A, B, bias, resid, C, M, N, K);
  else
    gemm_k<false><<<g, blk, 0, st>>>(A, B, bias, resid, C, M, N, K);
}

extern "C" void kernel_launch(void* const* d_in, const int* in_sizes, int n_in,
                              void* d_out, int out_size, void* d_ws, size_t ws_size,
                              hipStream_t stream) {
  const int*   tokens    = (const int*)d_in[0];
  const float* emb       = (const float*)d_in[1];
  const float* enc_wq    = (const float*)d_in[2];
  const float* enc_wk    = (const float*)d_in[3];
  const float* enc_wv    = (const float*)d_in[4];
  const float* enc_uo_w  = (const float*)d_in[5];
  const float* enc_uo_b  = (const float*)d_in[6];
  const float* enc_ln1_g = (const float*)d_in[7];
  const float* enc_ln1_b = (const float*)d_in[8];
  const float* enc_ln2_g = (const float*)d_in[9];
  const float* enc_ln2_b = (const float*)d_in[10];
  const float* enc_ff_w1 = (const float*)d_in[11];
  const float* enc_ff_b1 = (const float*)d_in[12];
  const float* enc_ff_w2 = (const float*)d_in[13];
  const float* enc_ff_b2 = (const float*)d_in[14];
  const float* dec_sa_wq = (const float*)d_in[15];
  const float* dec_sa_wk = (const float*)d_in[16];
  const float* dec_sa_wv = (const float*)d_in[17];
  const float* dec_sa_uo_w = (const float*)d_in[18];
  const float* dec_sa_uo_b = (const float*)d_in[19];
  const float* dec_ca_wq = (const float*)d_in[20];
  const float* dec_ca_wk = (const float*)d_in[21];
  const float* dec_ca_wv = (const float*)d_in[22];
  const float* dec_ca_uo_w = (const float*)d_in[23];
  const float* dec_ca_uo_b = (const float*)d_in[24];
  const float* dec_ln1_g = (const float*)d_in[25];
  const float* dec_ln1_b = (const float*)d_in[26];
  const float* dec_ln2_g = (const float*)d_in[27];
  const float* dec_ln2_b = (const float*)d_in[28];
  const float* dec_ln3_g = (const float*)d_in[29];
  const float* dec_ln3_b = (const float*)d_in[30];
  const float* dec_ff_w1 = (const float*)d_in[31];
  const float* dec_ff_b1 = (const float*)d_in[32];
  const float* dec_ff_w2 = (const float*)d_in[33];
  const float* dec_ff_b2 = (const float*)d_in[34];
  const float* ln_enc_g  = (const float*)d_in[35];
  const float* ln_enc_b  = (const float*)d_in[36];
  const float* ln_dec_g  = (const float*)d_in[37];
  const float* ln_dec_b  = (const float*)d_in[38];
  const float* head_w    = (const float*)d_in[39];
  const float* head_b    = (const float*)d_in[40];
  float* out = (float*)d_out;

  // workspace layout (all 256B-aligned)
  char* ws = (char*)d_ws;
  size_t off = 0;
  auto alloc = [&](size_t bytes) {
    void* p = ws + off;
    off += (bytes + 255) & ~(size_t)255;
    return p;
  };
  float* X    = (float*)alloc((size_t)Tt * Dd * 4);
  float* ENC  = (float*)alloc((size_t)Tt * Dd * 4);
  float* ENCF = (float*)alloc((size_t)Tt * Dd * 4);
  float* Hb   = (float*)alloc((size_t)Tt * Dd * 4);
  float* Qb   = (float*)alloc((size_t)Tt * Dd * 4);
  float* Kbf  = (float*)alloc((size_t)Tt * Dd * 4);
  float* Vbf  = (float*)alloc((size_t)Tt * Dd * 4);
  float* AO   = (float*)alloc((size_t)Tt * Dd * 4);
  float* Fb   = (float*)alloc((size_t)Tt * FFf * 4);
  float* WQ   = (float*)alloc((size_t)Dd * Dd * 4);
  float* WK   = (float*)alloc((size_t)Dd * Dd * 4);
  float* WV   = (float*)alloc((size_t)Dd * Dd * 4);

  const size_t W_QKV = (size_t)Hh * Dd * DHd;  // 262144
  const size_t W_UO  = (size_t)Dd * Dd;
  const size_t W_FF1 = (size_t)Dd * FFf;
  const size_t W_FF2 = (size_t)FFf * Dd;

  dim3 blk(256);
  dim3 repackG((Dd * Hh * DHd + 255) / 256);

  // embedding + positional encoding -> X and ENC
  embed_pe_k<<<Tt, blk, 0, stream>>>(tokens, emb, X, ENC);

  // -------- encoder --------
  for (int l = 0; l < 2; l++) {
    layernorm_k<<<Tt, blk, 0, stream>>>(ENC, enc_ln1_g + l * Dd, enc_ln1_b + l * Dd, Hb);
    repack_k<<<repackG, blk, 0, stream>>>(enc_wq + l * W_QKV, WQ);
    repack_k<<<repackG, blk, 0, stream>>>(enc_wk + l * W_QKV, WK);
    repack_k<<<repackG, blk, 0, stream>>>(enc_wv + l * W_QKV, WV);
    gemm_f32(stream, Hb, WQ, nullptr, nullptr, Qb, Tt, Dd, Dd, false);
    gemm_f32(stream, Hb, WK, nullptr, nullptr, Kbf, Tt, Dd, Dd, false);
    gemm_f32(stream, Hb, WV, nullptr, nullptr, Vbf, Tt, Dd, Dd, false);
    attn_k<<<Bb * Hh * Ss, blk, 0, stream>>>(Qb, Kbf, Vbf, AO);
    gemm_f32(stream, AO, enc_uo_w + l * W_UO, enc_uo_b + l * Dd, ENC, ENC, Tt, Dd, Dd, false);
    layernorm_k<<<Tt, blk, 0, stream>>>(ENC, enc_ln2_g + l * Dd, enc_ln2_b + l * Dd, Hb);
    gemm_f32(stream, Hb, enc_ff_w1 + l * W_FF1, enc_ff_b1 + l * FFf, nullptr, Fb, Tt, FFf, Dd, true);
    gemm_f32(stream, Fb, enc_ff_w2 + l * W_FF2, enc_ff_b2 + l * Dd, ENC, ENC, Tt, Dd, FFf, false);
  }
  layernorm_k<<<Tt, blk, 0, stream>>>(ENC, ln_enc_g, ln_enc_b, ENCF);

  // -------- decoder --------
  for (int l = 0; l < 2; l++) {
    // self-attention
    layernorm_k<<<Tt, blk, 0, stream>>>(X, dec_ln1_g + l * Dd, dec_ln1_b + l * Dd, Hb);
    repack_k<<<repackG, blk, 0, stream>>>(dec_sa_wq + l * W_QKV, WQ);
    repack_k<<<repackG, blk, 0, stream>>>(dec_sa_wk + l * W_QKV, WK);
    repack_k<<<repackG, blk, 0, stream>>>(dec_sa_wv + l * W_QKV, WV);
    gemm_f32(stream, Hb, WQ, nullptr, nullptr, Qb, Tt, Dd, Dd, false);
    gemm_f32(stream, Hb, WK, nullptr, nullptr, Kbf, Tt, Dd, Dd, false);
    gemm_f32(stream, Hb, WV, nullptr, nullptr, Vbf, Tt, Dd, Dd, false);
    attn_k<<<Bb * Hh * Ss, blk, 0, stream>>>(Qb, Kbf, Vbf, AO);
    gemm_f32(stream, AO, dec_sa_uo_w + l * W_UO, dec_sa_uo_b + l * Dd, X, X, Tt, Dd, Dd, false);
    // cross-attention (q from x, k/v from final encoder output; mask still causal)
    layernorm_k<<<Tt, blk, 0, stream>>>(X, dec_ln2_g + l * Dd, dec_ln2_b + l * Dd, Hb);
    repack_k<<<repackG, blk, 0, stream>>>(dec_ca_wq + l * W_QKV, WQ);
    repack_k<<<repackG, blk, 0, stream>>>(dec_ca_wk + l * W_QKV, WK);
    repack_k<<<repackG, blk, 0, stream>>>(dec_ca_wv + l * W_QKV, WV);
    gemm_f32(stream, Hb, WQ, nullptr, nullptr, Qb, Tt, Dd, Dd, false);
    gemm_f32(stream, ENCF, WK, nullptr, nullptr, Kbf, Tt, Dd, Dd, false);
    gemm_f32(stream, ENCF, WV, nullptr, nullptr, Vbf, Tt, Dd, Dd, false);
    attn_k<<<Bb * Hh * Ss, blk, 0, stream>>>(Qb, Kbf, Vbf, AO);
    gemm_f32(stream, AO, dec_ca_uo_w + l * W_UO, dec_ca_uo_b + l * Dd, X, X, Tt, Dd, Dd, false);
    // ffn
    layernorm_k<<<Tt, blk, 0, stream>>>(X, dec_ln3_g + l * Dd, dec_ln3_b + l * Dd, Hb);
    gemm_f32(stream, Hb, dec_ff_w1 + l * W_FF1, dec_ff_b1 + l * FFf, nullptr, Fb, Tt, FFf, Dd, true);
    gemm_f32(stream, Fb, dec_ff_w2 + l * W_FF2, dec_ff_b2 + l * Dd, X, X, Tt, Dd, FFf, false);
  }
  layernorm_k<<<Tt, blk, 0, stream>>>(X, ln_dec_g, ln_dec_b, Hb);

  // vocab head
  {
    dim3 g(Vv / 64, Tt / 64);
    gemm_k<false><<<g, blk, 0, stream>>>(Hb, head_w, head_b, nullptr, out, Tt, Vv, Dd);
  }
}

// Round 3
// 5092.250 us; speedup vs baseline: 1.5429x; 1.5429x over previous
//
#include <hip/hip_runtime.h>
#include <cstddef>
#include <cstdint>

constexpr int Vv = 32000, Dd = 512, Ss = 1024, Bb = 2, Hh = 8, DHd = 64, FFf = 2048;
constexpr int Tt = Bb * Ss;            // 2048 token rows
constexpr int QKVW = 3 * Dd;           // 1536 fused qkv width
constexpr float EPSf = 1e-5f;

typedef unsigned short ushort_t;
typedef short bf16x8 __attribute__((ext_vector_type(8)));
typedef float f32x4 __attribute__((ext_vector_type(4)));

__device__ __forceinline__ ushort_t f2b(float f) {
  unsigned int u = __float_as_uint(f);
  unsigned int r = (u + 0x7FFFu + ((u >> 16) & 1u)) >> 16;   // round-to-nearest-even
  return (ushort_t)r;
}

__device__ __forceinline__ void st_out(float* p, float v) { *p = v; }
__device__ __forceinline__ void st_out(ushort_t* p, float v) { *p = f2b(v); }

__device__ __forceinline__ void gload_lds16(const void* g, void* l) {
  __builtin_amdgcn_global_load_lds(
      (const __attribute__((address_space(1))) unsigned int*)g,
      (__attribute__((address_space(3))) unsigned int*)l, 16, 0, 0);
}

// ---------------------------------------------------------------- embed + PE
__global__ __launch_bounds__(256) void embed_pe_k(const int* __restrict__ tok,
                                                  const float* __restrict__ emb,
                                                  float* __restrict__ X,
                                                  float* __restrict__ ENC) {
  int row = blockIdx.x;
  int s = row & (Ss - 1);
  int t = tok[row];
  const float* e = emb + (size_t)t * Dd;
  for (int d = threadIdx.x; d < Dd; d += 256) {
    int i = d >> 1;
    float den = expf(-(float)(2 * i) * (9.210340371976184f / 512.0f));
    float ang = (float)s * den;
    float pe = (d & 1) ? cosf(ang) : sinf(ang);
    float v = e[d] + pe;
    X[(size_t)row * Dd + d] = v;
    ENC[(size_t)row * Dd + d] = v;
  }
}

// ------------------------------------------- layernorm (f32 in -> bf16 out)
__global__ __launch_bounds__(256) void layernorm_k(const float* __restrict__ in,
                                                   const float* __restrict__ g,
                                                   const float* __restrict__ b,
                                                   ushort_t* __restrict__ out) {
  int row = blockIdx.x;
  const float* x = in + (size_t)row * Dd;
  int tid = threadIdx.x;
  float v0 = x[tid], v1 = x[tid + 256];
  float s = v0 + v1, ss = v0 * v0 + v1 * v1;
  for (int o = 32; o; o >>= 1) {
    s  += __shfl_down(s, o, 64);
    ss += __shfl_down(ss, o, 64);
  }
  __shared__ float rs[4], rss[4];
  int wid = tid >> 6, lane = tid & 63;
  if (lane == 0) { rs[wid] = s; rss[wid] = ss; }
  __syncthreads();
  __shared__ float mean_s, inv_s;
  if (tid == 0) {
    float a = rs[0] + rs[1] + rs[2] + rs[3];
    float c = rss[0] + rss[1] + rss[2] + rss[3];
    float m = a / Dd;
    float var = c / Dd - m * m;
    mean_s = m;
    inv_s = rsqrtf(var + EPSf);
  }
  __syncthreads();
  float m = mean_s, inv = inv_s;
  out[(size_t)row * Dd + tid]       = f2b((v0 - m) * inv * g[tid]       + b[tid]);
  out[(size_t)row * Dd + tid + 256] = f2b((v1 - m) * inv * g[tid + 256] + b[tid + 256]);
}

// ------------------- pack wq/wk/wv [H,D,DH] f32 -> BT bf16 [1536][512] (N,K)
__global__ __launch_bounds__(256) void qkvpack_k(const float* __restrict__ wq,
                                                 const float* __restrict__ wk,
                                                 const float* __restrict__ wv,
                                                 ushort_t* __restrict__ out) {
  int idx = blockIdx.x * 256 + threadIdx.x;      // over 1536*512
  if (idx >= QKVW * Dd) return;
  int n = idx >> 9;          // 0..1535
  int k = idx & 511;
  const float* src = (n < Dd) ? wq : (n < 2 * Dd ? wk : wv);
  int np = n & (Dd - 1);
  int h = np >> 6, e = np & 63;
  out[idx] = f2b(src[((size_t)h * Dd + k) * DHd + e]);
}

// ----------------------- transpose-cast f32 [R][C] -> bf16 [C][R]  (N,K = C,R)
__global__ __launch_bounds__(256) void tcast_k(const float* __restrict__ in,
                                               ushort_t* __restrict__ out,
                                               int R, int C) {
  size_t idx = (size_t)blockIdx.x * 256 + threadIdx.x;  // over R*C, out-linear
  if (idx >= (size_t)R * C) return;
  int c = (int)(idx / R);
  int r = (int)(idx - (size_t)c * R);
  out[idx] = f2b(in[(size_t)r * C + c]);
}

// ---------------------------------------------------------------- MFMA GEMM
// C[M,N](ldc) = A[M,K]bf16 * BT[N,K]bf16^T  [+bias f32] [+resid f32] [relu]
// 128x128 tile, BK=64, 4 waves, mfma 16x16x32 bf16, global_load_lds staging.
template <typename OutT, bool RELU>
__global__ __launch_bounds__(256) void mfma_gemm_k(const ushort_t* __restrict__ A,
                                                   const ushort_t* __restrict__ BT,
                                                   const float* __restrict__ bias,
                                                   const float* __restrict__ resid,
                                                   OutT* __restrict__ C,
                                                   int M, int N, int K, int ldc) {
  __shared__ __align__(16) ushort_t As[128 * 64];
  __shared__ __align__(16) ushort_t Bs[128 * 64];
  int bm = blockIdx.y * 128, bn = blockIdx.x * 128;
  int tid = threadIdx.x;
  int lane = tid & 63, w = tid >> 6;
  int wr = w >> 1, wc = w & 1;     // wave -> 64x64 quadrant
  f32x4 acc[4][4];
#pragma unroll
  for (int m = 0; m < 4; m++)
#pragma unroll
    for (int n = 0; n < 4; n++) acc[m][n] = (f32x4){0.f, 0.f, 0.f, 0.f};

  const ushort_t* aBase = A + (size_t)bm * K;
  const ushort_t* bBase = BT + (size_t)bn * K;
  int lr = lane & 15;        // fragment row/col within 16
  int lk = (lane >> 4) * 8;  // fragment k offset

  for (int k0 = 0; k0 < K; k0 += 64) {
    __syncthreads();   // previous compute done before overwriting LDS
#pragma unroll
    for (int it = 0; it < 4; it++) {
      int cid = it * 256 + tid;
      int row = cid >> 3, c8 = cid & 7;
      gload_lds16(aBase + (size_t)row * K + k0 + c8 * 8, &As[cid * 8]);
    }
#pragma unroll
    for (int it = 0; it < 4; it++) {
      int cid = it * 256 + tid;
      int row = cid >> 3, c8 = cid & 7;
      gload_lds16(bBase + (size_t)row * K + k0 + c8 * 8, &Bs[cid * 8]);
    }
    __syncthreads();   // staging visible (vmcnt(0) drained by barrier)
#pragma unroll
    for (int kk = 0; kk < 64; kk += 32) {
      bf16x8 af[4], bfr[4];
#pragma unroll
      for (int m = 0; m < 4; m++)
        af[m] = *(const bf16x8*)&As[(wr * 64 + m * 16 + lr) * 64 + kk + lk];
#pragma unroll
      for (int n = 0; n < 4; n++)
        bfr[n] = *(const bf16x8*)&Bs[(wc * 64 + n * 16 + lr) * 64 + kk + lk];
#pragma unroll
      for (int m = 0; m < 4; m++)
#pragma unroll
        for (int n = 0; n < 4; n++)
          acc[m][n] = __builtin_amdgcn_mfma_f32_16x16x32_bf16(af[m], bfr[n], acc[m][n], 0, 0, 0);
    }
  }

  // epilogue: C/D layout col = lane&15, row = (lane>>4)*4 + reg  [m89]
  int rowg = (lane >> 4) * 4;
#pragma unroll
  for (int m = 0; m < 4; m++) {
    int row0 = bm + wr * 64 + m * 16 + rowg;
#pragma unroll
    for (int n = 0; n < 4; n++) {
      int col = bn + wc * 64 + n * 16 + lr;
      float bv = bias ? bias[col] : 0.0f;
#pragma unroll
      for (int r = 0; r < 4; r++) {
        int row = row0 + r;
        float v = acc[m][n][r] + bv;
        if (resid) v += resid[(size_t)row * ldc + col];
        if (RELU)  v = fmaxf(v, 0.0f);
        st_out(&C[(size_t)row * ldc + col], v);
      }
    }
  }
}

// ---------------------------------------------------------------- attention
// QKV fused f32 [T][1536]: Q at col 0, K at 512, V at 1024 (head h at h*64).
__global__ __launch_bounds__(256) void attn_k(const float* __restrict__ QKV,
                                              ushort_t* __restrict__ AO) {
  int idx = blockIdx.x;
  int s = idx & (Ss - 1);
  int h = (idx >> 10) & (Hh - 1);
  int b = idx >> 13;
  int tid = threadIdx.x;

  __shared__ float qs[DHd];
  __shared__ float p[Ss];
  __shared__ float red[256];

  const float* qp = QKV + ((size_t)(b * Ss + s) * QKVW + h * DHd);
  if (tid < DHd) qs[tid] = qp[tid];
  __syncthreads();

  const float* kbase = QKV + ((size_t)b * Ss * QKVW + Dd + h * DHd);
  float lmax = -INFINITY;
  for (int t = tid; t < Ss; t += 256) {
    float sc;
    if (t <= s) {
      const float* kp = kbase + (size_t)t * QKVW;
      float d = 0.0f;
#pragma unroll
      for (int e = 0; e < DHd; e++) d += qs[e] * kp[e];
      sc = d * 8.0f;   // faithful: scores MULTIPLIED by sqrt(DH)=8
    } else {
      sc = -INFINITY;
    }
    p[t] = sc;
    lmax = fmaxf(lmax, sc);
  }
  red[tid] = lmax;
  __syncthreads();
  for (int o = 128; o; o >>= 1) {
    if (tid < o) red[tid] = fmaxf(red[tid], red[tid + o]);
    __syncthreads();
  }
  float mx = red[0];
  __syncthreads();

  float lsum = 0.0f;
  for (int t = tid; t < Ss; t += 256) {
    float e = (t <= s) ? __expf(p[t] - mx) : 0.0f;
    p[t] = e;
    lsum += e;
  }
  red[tid] = lsum;
  __syncthreads();
  for (int o = 128; o; o >>= 1) {
    if (tid < o) red[tid] += red[tid + o];
    __syncthreads();
  }
  float denom = red[0];
  __syncthreads();

  int e = tid & 63, j = tid >> 6;
  const float* vbase = QKV + ((size_t)b * Ss * QKVW + 2 * Dd + h * DHd);
  float acc = 0.0f;
  int t0 = j * 256;
  int t1 = min(t0 + 256, s + 1);
  for (int t = t0; t < t1; t++) acc += p[t] * vbase[(size_t)t * QKVW + e];
  red[tid] = acc;
  __syncthreads();
  if (j == 0) {
    float tot = red[e] + red[e + 64] + red[e + 128] + red[e + 192];
    AO[(size_t)(b * Ss + s) * Dd + h * DHd + e] = f2b(tot / denom);
  }
}

// ---------------------------------------------------------------- host side
template <typename OutT, bool RELU>
static void gemm(hipStream_t st, const ushort_t* A, const ushort_t* BT, const float* bias,
                 const float* resid, OutT* C, int M, int N, int K, int ldc) {
  dim3 g(N / 128, M / 128), blk(256);
  mfma_gemm_k<OutT, RELU><<<g, blk, 0, st>>>(A, BT, bias, resid, C, M, N, K, ldc);
}

extern "C" void kernel_launch(void* const* d_in, const int* in_sizes, int n_in,
                              void* d_out, int out_size, void* d_ws, size_t ws_size,
                              hipStream_t stream) {
  const int*   tokens    = (const int*)d_in[0];
  const float* emb       = (const float*)d_in[1];
  const float* enc_wq    = (const float*)d_in[2];
  const float* enc_wk    = (const float*)d_in[3];
  const float* enc_wv    = (const float*)d_in[4];
  const float* enc_uo_w  = (const float*)d_in[5];
  const float* enc_uo_b  = (const float*)d_in[6];
  const float* enc_ln1_g = (const float*)d_in[7];
  const float* enc_ln1_b = (const float*)d_in[8];
  const float* enc_ln2_g = (const float*)d_in[9];
  const float* enc_ln2_b = (const float*)d_in[10];
  const float* enc_ff_w1 = (const float*)d_in[11];
  const float* enc_ff_b1 = (const float*)d_in[12];
  const float* enc_ff_w2 = (const float*)d_in[13];
  const float* enc_ff_b2 = (const float*)d_in[14];
  const float* dec_sa_wq = (const float*)d_in[15];
  const float* dec_sa_wk = (const float*)d_in[16];
  const float* dec_sa_wv = (const float*)d_in[17];
  const float* dec_sa_uo_w = (const float*)d_in[18];
  const float* dec_sa_uo_b = (const float*)d_in[19];
  const float* dec_ca_wq = (const float*)d_in[20];
  const float* dec_ca_wk = (const float*)d_in[21];
  const float* dec_ca_wv = (const float*)d_in[22];
  const float* dec_ca_uo_w = (const float*)d_in[23];
  const float* dec_ca_uo_b = (const float*)d_in[24];
  const float* dec_ln1_g = (const float*)d_in[25];
  const float* dec_ln1_b = (const float*)d_in[26];
  const float* dec_ln2_g = (const float*)d_in[27];
  const float* dec_ln2_b = (const float*)d_in[28];
  const float* dec_ln3_g = (const float*)d_in[29];
  const float* dec_ln3_b = (const float*)d_in[30];
  const float* dec_ff_w1 = (const float*)d_in[31];
  const float* dec_ff_b1 = (const float*)d_in[32];
  const float* dec_ff_w2 = (const float*)d_in[33];
  const float* dec_ff_b2 = (const float*)d_in[34];
  const float* ln_enc_g  = (const float*)d_in[35];
  const float* ln_enc_b  = (const float*)d_in[36];
  const float* ln_dec_g  = (const float*)d_in[37];
  const float* ln_dec_b  = (const float*)d_in[38];
  const float* head_w    = (const float*)d_in[39];
  const float* head_b    = (const float*)d_in[40];
  float* out = (float*)d_out;

  // ---- workspace layout (lean: ~41 MB; BThead overlaps X.. region at tail)
  char* ws = (char*)d_ws;
  size_t off = 0;
  auto alloc = [&](size_t bytes) {
    void* p = ws + off;
    off += (bytes + 255) & ~(size_t)255;
    return p;
  };
  ushort_t* Hb    = (ushort_t*)alloc((size_t)Tt * Dd * 2);     // LN out (bf16)
  ushort_t* ENCFb = (ushort_t*)alloc((size_t)Tt * Dd * 2);     // enc final (bf16)
  float*    X     = (float*)alloc((size_t)Tt * Dd * 4);
  float*    ENC   = (float*)alloc((size_t)Tt * Dd * 4);
  float*    QKV   = (float*)alloc((size_t)Tt * QKVW * 4);      // 12 MB
  ushort_t* AO    = (ushort_t*)alloc((size_t)Tt * Dd * 2);
  ushort_t* Fb    = (ushort_t*)alloc((size_t)Tt * FFf * 2);    // 8 MB
  ushort_t* BTqkv = (ushort_t*)alloc((size_t)QKVW * Dd * 2);
  ushort_t* BTuo  = (ushort_t*)alloc((size_t)Dd * Dd * 2);
  ushort_t* BTff1 = (ushort_t*)alloc((size_t)FFf * Dd * 2);
  ushort_t* BTff2 = (ushort_t*)alloc((size_t)Dd * FFf * 2);
  // head BT (32000x512 bf16 = 32.8 MB) reuses X..BTff2 region (36 MB), dead by then
  ushort_t* BThead = (ushort_t*)X;

  dim3 blk(256);
  dim3 qkvG((QKVW * Dd + 255) / 256);
  auto tcG = [](size_t n) { return dim3((unsigned)((n + 255) / 256)); };

  embed_pe_k<<<Tt, blk, 0, stream>>>(tokens, emb, X, ENC);

  // -------- encoder --------
  for (int l = 0; l < 2; l++) {
    layernorm_k<<<Tt, blk, 0, stream>>>(ENC, enc_ln1_g + l * Dd, enc_ln1_b + l * Dd, Hb);
    qkvpack_k<<<qkvG, blk, 0, stream>>>(enc_wq + (size_t)l * Hh * Dd * DHd,
                                        enc_wk + (size_t)l * Hh * Dd * DHd,
                                        enc_wv + (size_t)l * Hh * Dd * DHd, BTqkv);
    gemm<float, false>(stream, Hb, BTqkv, nullptr, nullptr, QKV, Tt, QKVW, Dd, QKVW);
    attn_k<<<Bb * Hh * Ss, blk, 0, stream>>>(QKV, AO);
    tcast_k<<<tcG((size_t)Dd * Dd), blk, 0, stream>>>(enc_uo_w + (size_t)l * Dd * Dd, BTuo, Dd, Dd);
    gemm<float, false>(stream, AO, BTuo, enc_uo_b + l * Dd, ENC, ENC, Tt, Dd, Dd, Dd);
    layernorm_k<<<Tt, blk, 0, stream>>>(ENC, enc_ln2_g + l * Dd, enc_ln2_b + l * Dd, Hb);
    tcast_k<<<tcG((size_t)Dd * FFf), blk, 0, stream>>>(enc_ff_w1 + (size_t)l * Dd * FFf, BTff1, Dd, FFf);
    gemm<ushort_t, true>(stream, Hb, BTff1, enc_ff_b1 + l * FFf, nullptr, Fb, Tt, FFf, Dd, FFf);
    tcast_k<<<tcG((size_t)FFf * Dd), blk, 0, stream>>>(enc_ff_w2 + (size_t)l * FFf * Dd, BTff2, FFf, Dd);
    gemm<float, false>(stream, Fb, BTff2, enc_ff_b2 + l * Dd, ENC, ENC, Tt, Dd, FFf, Dd);
  }
  layernorm_k<<<Tt, blk, 0, stream>>>(ENC, ln_enc_g, ln_enc_b, ENCFb);

  // -------- decoder --------
  for (int l = 0; l < 2; l++) {
    // self-attention
    layernorm_k<<<Tt, blk, 0, stream>>>(X, dec_ln1_g + l * Dd, dec_ln1_b + l * Dd, Hb);
    qkvpack_k<<<qkvG, blk, 0, stream>>>(dec_sa_wq + (size_t)l * Hh * Dd * DHd,
                                        dec_sa_wk + (size_t)l * Hh * Dd * DHd,
                                        dec_sa_wv + (size_t)l * Hh * Dd * DHd, BTqkv);
    gemm<float, false>(stream, Hb, BTqkv, nullptr, nullptr, QKV, Tt, QKVW, Dd, QKVW);
    attn_k<<<Bb * Hh * Ss, blk, 0, stream>>>(QKV, AO);
    tcast_k<<<tcG((size_t)Dd * Dd), blk, 0, stream>>>(dec_sa_uo_w + (size_t)l * Dd * Dd, BTuo, Dd, Dd);
    gemm<float, false>(stream, AO, BTuo, dec_sa_uo_b + l * Dd, X, X, Tt, Dd, Dd, Dd);
    // cross-attention: Q from LN(x), K/V from ENCFb (still causal-masked)
    layernorm_k<<<Tt, blk, 0, stream>>>(X, dec_ln2_g + l * Dd, dec_ln2_b + l * Dd, Hb);
    qkvpack_k<<<qkvG, blk, 0, stream>>>(dec_ca_wq + (size_t)l * Hh * Dd * DHd,
                                        dec_ca_wk + (size_t)l * Hh * Dd * DHd,
                                        dec_ca_wv + (size_t)l * Hh * Dd * DHd, BTqkv);
    gemm<float, false>(stream, Hb, BTqkv, nullptr, nullptr, QKV, Tt, Dd, Dd, QKVW);
    gemm<float, false>(stream, ENCFb, BTqkv + (size_t)Dd * Dd, nullptr, nullptr,
                       QKV + Dd, Tt, 2 * Dd, Dd, QKVW);
    attn_k<<<Bb * Hh * Ss, blk, 0, stream>>>(QKV, AO);
    tcast_k<<<tcG((size_t)Dd * Dd), blk, 0, stream>>>(dec_ca_uo_w + (size_t)l * Dd * Dd, BTuo, Dd, Dd);
    gemm<float, false>(stream, AO, BTuo, dec_ca_uo_b + l * Dd, X, X, Tt, Dd, Dd, Dd);
    // ffn
    layernorm_k<<<Tt, blk, 0, stream>>>(X, dec_ln3_g + l * Dd, dec_ln3_b + l * Dd, Hb);
    tcast_k<<<tcG((size_t)Dd * FFf), blk, 0, stream>>>(dec_ff_w1 + (size_t)l * Dd * FFf, BTff1, Dd, FFf);
    gemm<ushort_t, true>(stream, Hb, BTff1, dec_ff_b1 + l * FFf, nullptr, Fb, Tt, FFf, Dd, FFf);
    tcast_k<<<tcG((size_t)FFf * Dd), blk, 0, stream>>>(dec_ff_w2 + (size_t)l * FFf * Dd, BTff2, FFf, Dd);
    gemm<float, false>(stream, Fb, BTff2, dec_ff_b2 + l * Dd, X, X, Tt, Dd, FFf, Dd);
  }
  layernorm_k<<<Tt, blk, 0, stream>>>(X, ln_dec_g, ln_dec_b, Hb);  // X dead after this

  // vocab head: transpose-cast head_w into the dead X.. region, then MFMA GEMM
  tcast_k<<<tcG((size_t)Dd * Vv), blk, 0, stream>>>(head_w, BThead, Dd, Vv);
  gemm<float, false>(stream, Hb, BThead, head_b, nullptr, out, Tt, Vv, Dd, Vv);
}

// Round 4
// 1241.458 us; speedup vs baseline: 6.3285x; 4.1018x over previous
//
#include <hip/hip_runtime.h>
#include <cstddef>
#include <cstdint>

constexpr int Vv = 32000, Dd = 512, Ss = 1024, Bb = 2, Hh = 8, DHd = 64, FFf = 2048;
constexpr int Tt = Bb * Ss;            // 2048 token rows
constexpr int QKVW = 3 * Dd;           // 1536 fused qkv width
constexpr float EPSf = 1e-5f;

typedef unsigned short ushort_t;
typedef short bf16x8 __attribute__((ext_vector_type(8)));
typedef short short4v __attribute__((ext_vector_type(4)));
typedef float f32x4 __attribute__((ext_vector_type(4)));

__device__ __forceinline__ ushort_t f2b(float f) {
  unsigned int u = __float_as_uint(f);
  unsigned int r = (u + 0x7FFFu + ((u >> 16) & 1u)) >> 16;   // round-to-nearest-even
  return (ushort_t)r;
}
__device__ __forceinline__ float bits2f(ushort_t u) {
  return __uint_as_float((unsigned int)u << 16);
}

__device__ __forceinline__ void st_out(float* p, float v) { *p = v; }
__device__ __forceinline__ void st_out(ushort_t* p, float v) { *p = f2b(v); }

__device__ __forceinline__ void gload_lds16(const void* g, void* l) {
  __builtin_amdgcn_global_load_lds(
      (const __attribute__((address_space(1))) unsigned int*)g,
      (__attribute__((address_space(3))) unsigned int*)l, 16, 0, 0);
}

// ---------------------------------------------------------------- embed + PE
__global__ __launch_bounds__(256) void embed_pe_k(const int* __restrict__ tok,
                                                  const float* __restrict__ emb,
                                                  float* __restrict__ X,
                                                  float* __restrict__ ENC) {
  int row = blockIdx.x;
  int s = row & (Ss - 1);
  int t = tok[row];
  const float* e = emb + (size_t)t * Dd;
  for (int d = threadIdx.x; d < Dd; d += 256) {
    int i = d >> 1;
    float den = expf(-(float)(2 * i) * (9.210340371976184f / 512.0f));
    float ang = (float)s * den;
    float pe = (d & 1) ? cosf(ang) : sinf(ang);
    float v = e[d] + pe;
    X[(size_t)row * Dd + d] = v;
    ENC[(size_t)row * Dd + d] = v;
  }
}

// ------------------------------------------- layernorm (f32 in -> bf16 out)
__global__ __launch_bounds__(256) void layernorm_k(const float* __restrict__ in,
                                                   const float* __restrict__ g,
                                                   const float* __restrict__ b,
                                                   ushort_t* __restrict__ out) {
  int row = blockIdx.x;
  const float* x = in + (size_t)row * Dd;
  int tid = threadIdx.x;
  float v0 = x[tid], v1 = x[tid + 256];
  float s = v0 + v1, ss = v0 * v0 + v1 * v1;
  for (int o = 32; o; o >>= 1) {
    s  += __shfl_down(s, o, 64);
    ss += __shfl_down(ss, o, 64);
  }
  __shared__ float rs[4], rss[4];
  int wid = tid >> 6, lane = tid & 63;
  if (lane == 0) { rs[wid] = s; rss[wid] = ss; }
  __syncthreads();
  __shared__ float mean_s, inv_s;
  if (tid == 0) {
    float a = rs[0] + rs[1] + rs[2] + rs[3];
    float c = rss[0] + rss[1] + rss[2] + rss[3];
    float m = a / Dd;
    float var = c / Dd - m * m;
    mean_s = m;
    inv_s = rsqrtf(var + EPSf);
  }
  __syncthreads();
  float m = mean_s, inv = inv_s;
  out[(size_t)row * Dd + tid]       = f2b((v0 - m) * inv * g[tid]       + b[tid]);
  out[(size_t)row * Dd + tid + 256] = f2b((v1 - m) * inv * g[tid + 256] + b[tid + 256]);
}

// ------------------- pack wq/wk/wv [H,D,DH] f32 -> BT bf16 [1536][512] (N,K)
__global__ __launch_bounds__(256) void qkvpack_k(const float* __restrict__ wq,
                                                 const float* __restrict__ wk,
                                                 const float* __restrict__ wv,
                                                 ushort_t* __restrict__ out) {
  int idx = blockIdx.x * 256 + threadIdx.x;      // over 1536*512
  if (idx >= QKVW * Dd) return;
  int n = idx >> 9;          // 0..1535
  int k = idx & 511;
  const float* src = (n < Dd) ? wq : (n < 2 * Dd ? wk : wv);
  int np = n & (Dd - 1);
  int h = np >> 6, e = np & 63;
  out[idx] = f2b(src[((size_t)h * Dd + k) * DHd + e]);
}

// ----------------------- transpose-cast f32 [R][C] -> bf16 [C][R]  (N,K = C,R)
__global__ __launch_bounds__(256) void tcast_k(const float* __restrict__ in,
                                               ushort_t* __restrict__ out,
                                               int R, int C) {
  size_t idx = (size_t)blockIdx.x * 256 + threadIdx.x;  // over R*C, out-linear
  if (idx >= (size_t)R * C) return;
  int c = (int)(idx / R);
  int r = (int)(idx - (size_t)c * R);
  out[idx] = f2b(in[(size_t)r * C + c]);
}

// ---------------------------------------------------------------- MFMA GEMM
// C[M,N](ldc) = A[M,K]bf16 * BT[N,K]bf16^T  [+bias f32] [+resid f32] [relu]
template <typename OutT, bool RELU>
__global__ __launch_bounds__(256) void mfma_gemm_k(const ushort_t* __restrict__ A,
                                                   const ushort_t* __restrict__ BT,
                                                   const float* __restrict__ bias,
                                                   const float* __restrict__ resid,
                                                   OutT* __restrict__ C,
                                                   int M, int N, int K, int ldc) {
  __shared__ __align__(16) ushort_t As[128 * 64];
  __shared__ __align__(16) ushort_t Bs[128 * 64];
  int bm = blockIdx.y * 128, bn = blockIdx.x * 128;
  int tid = threadIdx.x;
  int lane = tid & 63, w = tid >> 6;
  int wr = w >> 1, wc = w & 1;     // wave -> 64x64 quadrant
  f32x4 acc[4][4];
#pragma unroll
  for (int m = 0; m < 4; m++)
#pragma unroll
    for (int n = 0; n < 4; n++) acc[m][n] = (f32x4){0.f, 0.f, 0.f, 0.f};

  const ushort_t* aBase = A + (size_t)bm * K;
  const ushort_t* bBase = BT + (size_t)bn * K;
  int lr = lane & 15;        // fragment row/col within 16
  int lk = (lane >> 4) * 8;  // fragment k offset

  for (int k0 = 0; k0 < K; k0 += 64) {
    __syncthreads();
#pragma unroll
    for (int it = 0; it < 4; it++) {
      int cid = it * 256 + tid;
      int row = cid >> 3, c8 = cid & 7;
      gload_lds16(aBase + (size_t)row * K + k0 + c8 * 8, &As[cid * 8]);
    }
#pragma unroll
    for (int it = 0; it < 4; it++) {
      int cid = it * 256 + tid;
      int row = cid >> 3, c8 = cid & 7;
      gload_lds16(bBase + (size_t)row * K + k0 + c8 * 8, &Bs[cid * 8]);
    }
    __syncthreads();
#pragma unroll
    for (int kk = 0; kk < 64; kk += 32) {
      bf16x8 af[4], bfr[4];
#pragma unroll
      for (int m = 0; m < 4; m++)
        af[m] = *(const bf16x8*)&As[(wr * 64 + m * 16 + lr) * 64 + kk + lk];
#pragma unroll
      for (int n = 0; n < 4; n++)
        bfr[n] = *(const bf16x8*)&Bs[(wc * 64 + n * 16 + lr) * 64 + kk + lk];
#pragma unroll
      for (int m = 0; m < 4; m++)
#pragma unroll
        for (int n = 0; n < 4; n++)
          acc[m][n] = __builtin_amdgcn_mfma_f32_16x16x32_bf16(af[m], bfr[n], acc[m][n], 0, 0, 0);
    }
  }

  int rowg = (lane >> 4) * 4;
#pragma unroll
  for (int m = 0; m < 4; m++) {
    int row0 = bm + wr * 64 + m * 16 + rowg;
#pragma unroll
    for (int n = 0; n < 4; n++) {
      int col = bn + wc * 64 + n * 16 + lr;
      float bv = bias ? bias[col] : 0.0f;
#pragma unroll
      for (int r = 0; r < 4; r++) {
        int row = row0 + r;
        float v = acc[m][n][r] + bv;
        if (resid) v += resid[(size_t)row * ldc + col];
        if (RELU)  v = fmaxf(v, 0.0f);
        st_out(&C[(size_t)row * ldc + col], v);
      }
    }
  }
}

// --------------------------------------------------- fused flash attention
// grid: qt + 16*(h + 8*b); block 256 (4 waves, each 16 q-rows of a 64-row tile)
// QKV f32 [T][1536]: Q col 0, K col 512, V col 1024 (+ h*64).
// Scores = (Q.K^T) * 8 (faithful sqrt(DH) MULTIPLY), causal mask, softmax, PV.
// Q/K staged hi/lo bf16 (3-mfma split: score err ~2^-17); LDS XOR-swizzled (T2).
__global__ __launch_bounds__(256) void fattn_k(const float* __restrict__ QKV,
                                               ushort_t* __restrict__ AO) {
  int qt = blockIdx.x & 15;
  int h  = (blockIdx.x >> 4) & 7;
  int b  = blockIdx.x >> 7;
  int q0 = qt * 64;
  int tid = threadIdx.x;
  int lane = tid & 63, w = tid >> 6;
  int g = lane >> 4, c = lane & 15;

  __shared__ __align__(16) ushort_t Qh[64 * 64], Ql[64 * 64];
  __shared__ __align__(16) ushort_t Kh[64 * 64], Kl[64 * 64];
  __shared__ __align__(16) ushort_t VT[64 * 64];
  __shared__ __align__(16) ushort_t Ps[4][16 * 64];

  // ---- stage Q (hi/lo, swizzled): thread -> row tid>>2, cols (tid&3)*16..+16
  {
    int row = tid >> 2, c0 = (tid & 3) * 16;
    const float* qb = QKV + ((size_t)(b * Ss + q0 + row) * QKVW + h * DHd + c0);
#pragma unroll
    for (int i = 0; i < 4; i++) {
      float4 v = *(const float4*)(qb + i * 4);
      int col = c0 + i * 4;
      int sc = col ^ ((row & 7) << 3);
      ushort_t h0 = f2b(v.x), h1 = f2b(v.y), h2 = f2b(v.z), h3 = f2b(v.w);
      short4v hv = {(short)h0, (short)h1, (short)h2, (short)h3};
      short4v lv = {(short)f2b(v.x - bits2f(h0)), (short)f2b(v.y - bits2f(h1)),
                    (short)f2b(v.z - bits2f(h2)), (short)f2b(v.w - bits2f(h3))};
      *(short4v*)&Qh[row * 64 + sc] = hv;
      *(short4v*)&Ql[row * 64 + sc] = lv;
    }
  }

  f32x4 Oa[4];
#pragma unroll
  for (int n = 0; n < 4; n++) Oa[n] = (f32x4){0.f, 0.f, 0.f, 0.f};
  float mrow[4] = {-INFINITY, -INFINITY, -INFINITY, -INFINITY};
  float lrow[4] = {0.f, 0.f, 0.f, 0.f};

  int nkv = qt + 1;
  for (int it = 0; it < nkv; it++) {
    int t0 = it * 64;
    __syncthreads();   // Q ready (it=0) / previous tile compute done
    // ---- stage K hi/lo + V^T
    {
      int row = tid >> 2, c0 = (tid & 3) * 16;
      const float* kb = QKV + ((size_t)(b * Ss + t0 + row) * QKVW + Dd + h * DHd + c0);
      const float* vb = kb + Dd;   // V at +512 cols
#pragma unroll
      for (int i = 0; i < 4; i++) {
        float4 v = *(const float4*)(kb + i * 4);
        int col = c0 + i * 4;
        int sc = col ^ ((row & 7) << 3);
        ushort_t h0 = f2b(v.x), h1 = f2b(v.y), h2 = f2b(v.z), h3 = f2b(v.w);
        short4v hv = {(short)h0, (short)h1, (short)h2, (short)h3};
        short4v lv = {(short)f2b(v.x - bits2f(h0)), (short)f2b(v.y - bits2f(h1)),
                      (short)f2b(v.z - bits2f(h2)), (short)f2b(v.w - bits2f(h3))};
        *(short4v*)&Kh[row * 64 + sc] = hv;
        *(short4v*)&Kl[row * 64 + sc] = lv;
      }
#pragma unroll
      for (int i = 0; i < 4; i++) {
        float4 v = *(const float4*)(vb + i * 4);
        int e0 = c0 + i * 4;
        // VT[e][t] with col swizzle by e
        VT[(e0 + 0) * 64 + (row ^ (((e0 + 0) & 7) << 3))] = f2b(v.x);
        VT[(e0 + 1) * 64 + (row ^ (((e0 + 1) & 7) << 3))] = f2b(v.y);
        VT[(e0 + 2) * 64 + (row ^ (((e0 + 2) & 7) << 3))] = f2b(v.z);
        VT[(e0 + 3) * 64 + (row ^ (((e0 + 3) & 7) << 3))] = f2b(v.w);
      }
    }
    __syncthreads();

    // ---- QK^T: wave w rows q0+w*16..+15 ; A row = c, k offs = g*8
    int arow = w * 16 + c;
    int ksw0 = (0 + g * 8) ^ ((c & 7) << 3);
    int ksw1 = (32 + g * 8) ^ ((c & 7) << 3);
    bf16x8 qh0 = *(const bf16x8*)&Qh[arow * 64 + ksw0];
    bf16x8 qh1 = *(const bf16x8*)&Qh[arow * 64 + ksw1];
    bf16x8 ql0 = *(const bf16x8*)&Ql[arow * 64 + ksw0];
    bf16x8 ql1 = *(const bf16x8*)&Ql[arow * 64 + ksw1];

    f32x4 sfr[4];
#pragma unroll
    for (int n = 0; n < 4; n++) {
      int brow = n * 16 + c;
      int bs0 = (0 + g * 8) ^ ((c & 7) << 3);
      int bs1 = (32 + g * 8) ^ ((c & 7) << 3);
      bf16x8 kh0 = *(const bf16x8*)&Kh[brow * 64 + bs0];
      bf16x8 kh1 = *(const bf16x8*)&Kh[brow * 64 + bs1];
      bf16x8 kl0 = *(const bf16x8*)&Kl[brow * 64 + bs0];
      bf16x8 kl1 = *(const bf16x8*)&Kl[brow * 64 + bs1];
      f32x4 a = (f32x4){0.f, 0.f, 0.f, 0.f};
      a = __builtin_amdgcn_mfma_f32_16x16x32_bf16(qh0, kl0, a, 0, 0, 0);
      a = __builtin_amdgcn_mfma_f32_16x16x32_bf16(qh1, kl1, a, 0, 0, 0);
      a = __builtin_amdgcn_mfma_f32_16x16x32_bf16(ql0, kh0, a, 0, 0, 0);
      a = __builtin_amdgcn_mfma_f32_16x16x32_bf16(ql1, kh1, a, 0, 0, 0);
      a = __builtin_amdgcn_mfma_f32_16x16x32_bf16(qh0, kh0, a, 0, 0, 0);
      a = __builtin_amdgcn_mfma_f32_16x16x32_bf16(qh1, kh1, a, 0, 0, 0);
      sfr[n] = a;
    }

    // scale by 8, causal mask (only possible on diagonal tile t0 == q0)
#pragma unroll
    for (int n = 0; n < 4; n++) {
#pragma unroll
      for (int r = 0; r < 4; r++) sfr[n][r] *= 8.0f;
    }
    if (t0 == q0) {
#pragma unroll
      for (int n = 0; n < 4; n++) {
        int t = t0 + n * 16 + c;
#pragma unroll
        for (int r = 0; r < 4; r++) {
          int s = q0 + w * 16 + g * 4 + r;
          if (t > s) sfr[n][r] = -INFINITY;
        }
      }
    }

    // ---- online softmax (row lives in 16 lanes of group g)
    float pnew[4], scold[4];
#pragma unroll
    for (int r = 0; r < 4; r++) {
      float tm = fmaxf(fmaxf(sfr[0][r], sfr[1][r]), fmaxf(sfr[2][r], sfr[3][r]));
      tm = fmaxf(tm, __shfl_xor(tm, 1));
      tm = fmaxf(tm, __shfl_xor(tm, 2));
      tm = fmaxf(tm, __shfl_xor(tm, 4));
      tm = fmaxf(tm, __shfl_xor(tm, 8));
      float mn = fmaxf(mrow[r], tm);
      scold[r] = __expf(mrow[r] - mn);   // exp(-inf)=0 on first tile
      mrow[r] = mn;
      pnew[r] = mn;
    }
#pragma unroll
    for (int n = 0; n < 4; n++) {
#pragma unroll
      for (int r = 0; r < 4; r++) sfr[n][r] = __expf(sfr[n][r] - pnew[r]);
    }
    float rsum[4];
#pragma unroll
    for (int r = 0; r < 4; r++) {
      float s = sfr[0][r] + sfr[1][r] + sfr[2][r] + sfr[3][r];
      s += __shfl_xor(s, 1);
      s += __shfl_xor(s, 2);
      s += __shfl_xor(s, 4);
      s += __shfl_xor(s, 8);
      lrow[r] = lrow[r] * scold[r] + s;
    }

    // ---- P -> bf16 LDS (per-wave tile, swizzled)
#pragma unroll
    for (int n = 0; n < 4; n++) {
#pragma unroll
      for (int r = 0; r < 4; r++) {
        int prow = g * 4 + r;
        Ps[w][prow * 64 + ((n * 16 + c) ^ ((prow & 7) << 3))] = f2b(sfr[n][r]);
      }
    }

    // ---- rescale O
#pragma unroll
    for (int n = 0; n < 4; n++) {
#pragma unroll
      for (int r = 0; r < 4; r++) Oa[n][r] *= scold[r];
    }

    // ---- PV: A = P (row=c), B = VT (row = dh)
    bf16x8 pa0 = *(const bf16x8*)&Ps[w][c * 64 + ksw0];
    bf16x8 pa1 = *(const bf16x8*)&Ps[w][c * 64 + ksw1];
#pragma unroll
    for (int n = 0; n < 4; n++) {
      int vrow = n * 16 + c;
      bf16x8 v0 = *(const bf16x8*)&VT[vrow * 64 + ksw0];
      bf16x8 v1 = *(const bf16x8*)&VT[vrow * 64 + ksw1];
      Oa[n] = __builtin_amdgcn_mfma_f32_16x16x32_bf16(pa0, v0, Oa[n], 0, 0, 0);
      Oa[n] = __builtin_amdgcn_mfma_f32_16x16x32_bf16(pa1, v1, Oa[n], 0, 0, 0);
    }
  }

  // ---- epilogue: AO[row][h*64 + dh] = O / l
#pragma unroll
  for (int r = 0; r < 4; r++) {
    float inv = 1.0f / lrow[r];
    int row = b * Ss + q0 + w * 16 + g * 4 + r;
#pragma unroll
    for (int n = 0; n < 4; n++) {
      AO[(size_t)row * Dd + h * DHd + n * 16 + c] = f2b(Oa[n][r] * inv);
    }
  }
}

// ---------------------------------------------------------------- host side
template <typename OutT, bool RELU>
static void gemm(hipStream_t st, const ushort_t* A, const ushort_t* BT, const float* bias,
                 const float* resid, OutT* C, int M, int N, int K, int ldc) {
  dim3 g(N / 128, M / 128), blk(256);
  mfma_gemm_k<OutT, RELU><<<g, blk, 0, st>>>(A, BT, bias, resid, C, M, N, K, ldc);
}

extern "C" void kernel_launch(void* const* d_in, const int* in_sizes, int n_in,
                              void* d_out, int out_size, void* d_ws, size_t ws_size,
                              hipStream_t stream) {
  const int*   tokens    = (const int*)d_in[0];
  const float* emb       = (const float*)d_in[1];
  const float* enc_wq    = (const float*)d_in[2];
  const float* enc_wk    = (const float*)d_in[3];
  const float* enc_wv    = (const float*)d_in[4];
  const float* enc_uo_w  = (const float*)d_in[5];
  const float* enc_uo_b  = (const float*)d_in[6];
  const float* enc_ln1_g = (const float*)d_in[7];
  const float* enc_ln1_b = (const float*)d_in[8];
  const float* enc_ln2_g = (const float*)d_in[9];
  const float* enc_ln2_b = (const float*)d_in[10];
  const float* enc_ff_w1 = (const float*)d_in[11];
  const float* enc_ff_b1 = (const float*)d_in[12];
  const float* enc_ff_w2 = (const float*)d_in[13];
  const float* enc_ff_b2 = (const float*)d_in[14];
  const float* dec_sa_wq = (const float*)d_in[15];
  const float* dec_sa_wk = (const float*)d_in[16];
  const float* dec_sa_wv = (const float*)d_in[17];
  const float* dec_sa_uo_w = (const float*)d_in[18];
  const float* dec_sa_uo_b = (const float*)d_in[19];
  const float* dec_ca_wq = (const float*)d_in[20];
  const float* dec_ca_wk = (const float*)d_in[21];
  const float* dec_ca_wv = (const float*)d_in[22];
  const float* dec_ca_uo_w = (const float*)d_in[23];
  const float* dec_ca_uo_b = (const float*)d_in[24];
  const float* dec_ln1_g = (const float*)d_in[25];
  const float* dec_ln1_b = (const float*)d_in[26];
  const float* dec_ln2_g = (const float*)d_in[27];
  const float* dec_ln2_b = (const float*)d_in[28];
  const float* dec_ln3_g = (const float*)d_in[29];
  const float* dec_ln3_b = (const float*)d_in[30];
  const float* dec_ff_w1 = (const float*)d_in[31];
  const float* dec_ff_b1 = (const float*)d_in[32];
  const float* dec_ff_w2 = (const float*)d_in[33];
  const float* dec_ff_b2 = (const float*)d_in[34];
  const float* ln_enc_g  = (const float*)d_in[35];
  const float* ln_enc_b  = (const float*)d_in[36];
  const float* ln_dec_g  = (const float*)d_in[37];
  const float* ln_dec_b  = (const float*)d_in[38];
  const float* head_w    = (const float*)d_in[39];
  const float* head_b    = (const float*)d_in[40];
  float* out = (float*)d_out;

  char* ws = (char*)d_ws;
  size_t off = 0;
  auto alloc = [&](size_t bytes) {
    void* p = ws + off;
    off += (bytes + 255) & ~(size_t)255;
    return p;
  };
  ushort_t* Hb    = (ushort_t*)alloc((size_t)Tt * Dd * 2);
  ushort_t* ENCFb = (ushort_t*)alloc((size_t)Tt * Dd * 2);
  float*    X     = (float*)alloc((size_t)Tt * Dd * 4);
  float*    ENC   = (float*)alloc((size_t)Tt * Dd * 4);
  float*    QKV   = (float*)alloc((size_t)Tt * QKVW * 4);
  ushort_t* AO    = (ushort_t*)alloc((size_t)Tt * Dd * 2);
  ushort_t* Fb    = (ushort_t*)alloc((size_t)Tt * FFf * 2);
  ushort_t* BTqkv = (ushort_t*)alloc((size_t)QKVW * Dd * 2);
  ushort_t* BTuo  = (ushort_t*)alloc((size_t)Dd * Dd * 2);
  ushort_t* BTff1 = (ushort_t*)alloc((size_t)FFf * Dd * 2);
  ushort_t* BTff2 = (ushort_t*)alloc((size_t)Dd * FFf * 2);
  ushort_t* BThead = (ushort_t*)X;   // head BT reuses dead X.. region at tail

  dim3 blk(256);
  dim3 qkvG((QKVW * Dd + 255) / 256);
  dim3 attnG(Bb * Hh * (Ss / 64));   // 256 blocks
  auto tcG = [](size_t n) { return dim3((unsigned)((n + 255) / 256)); };

  embed_pe_k<<<Tt, blk, 0, stream>>>(tokens, emb, X, ENC);

  // -------- encoder --------
  for (int l = 0; l < 2; l++) {
    layernorm_k<<<Tt, blk, 0, stream>>>(ENC, enc_ln1_g + l * Dd, enc_ln1_b + l * Dd, Hb);
    qkvpack_k<<<qkvG, blk, 0, stream>>>(enc_wq + (size_t)l * Hh * Dd * DHd,
                                        enc_wk + (size_t)l * Hh * Dd * DHd,
                                        enc_wv + (size_t)l * Hh * Dd * DHd, BTqkv);
    gemm<float, false>(stream, Hb, BTqkv, nullptr, nullptr, QKV, Tt, QKVW, Dd, QKVW);
    fattn_k<<<attnG, blk, 0, stream>>>(QKV, AO);
    tcast_k<<<tcG((size_t)Dd * Dd), blk, 0, stream>>>(enc_uo_w + (size_t)l * Dd * Dd, BTuo, Dd, Dd);
    gemm<float, false>(stream, AO, BTuo, enc_uo_b + l * Dd, ENC, ENC, Tt, Dd, Dd, Dd);
    layernorm_k<<<Tt, blk, 0, stream>>>(ENC, enc_ln2_g + l * Dd, enc_ln2_b + l * Dd, Hb);
    tcast_k<<<tcG((size_t)Dd * FFf), blk, 0, stream>>>(enc_ff_w1 + (size_t)l * Dd * FFf, BTff1, Dd, FFf);
    gemm<ushort_t, true>(stream, Hb, BTff1, enc_ff_b1 + l * FFf, nullptr, Fb, Tt, FFf, Dd, FFf);
    tcast_k<<<tcG((size_t)FFf * Dd), blk, 0, stream>>>(enc_ff_w2 + (size_t)l * FFf * Dd, BTff2, FFf, Dd);
    gemm<float, false>(stream, Fb, BTff2, enc_ff_b2 + l * Dd, ENC, ENC, Tt, Dd, FFf, Dd);
  }
  layernorm_k<<<Tt, blk, 0, stream>>>(ENC, ln_enc_g, ln_enc_b, ENCFb);

  // -------- decoder --------
  for (int l = 0; l < 2; l++) {
    layernorm_k<<<Tt, blk, 0, stream>>>(X, dec_ln1_g + l * Dd, dec_ln1_b + l * Dd, Hb);
    qkvpack_k<<<qkvG, blk, 0, stream>>>(dec_sa_wq + (size_t)l * Hh * Dd * DHd,
                                        dec_sa_wk + (size_t)l * Hh * Dd * DHd,
                                        dec_sa_wv + (size_t)l * Hh * Dd * DHd, BTqkv);
    gemm<float, false>(stream, Hb, BTqkv, nullptr, nullptr, QKV, Tt, QKVW, Dd, QKVW);
    fattn_k<<<attnG, blk, 0, stream>>>(QKV, AO);
    tcast_k<<<tcG((size_t)Dd * Dd), blk, 0, stream>>>(dec_sa_uo_w + (size_t)l * Dd * Dd, BTuo, Dd, Dd);
    gemm<float, false>(stream, AO, BTuo, dec_sa_uo_b + l * Dd, X, X, Tt, Dd, Dd, Dd);
    // cross-attention: Q from LN(x), K/V from ENCFb (faithful causal mask)
    layernorm_k<<<Tt, blk, 0, stream>>>(X, dec_ln2_g + l * Dd, dec_ln2_b + l * Dd, Hb);
    qkvpack_k<<<qkvG, blk, 0, stream>>>(dec_ca_wq + (size_t)l * Hh * Dd * DHd,
                                        dec_ca_wk + (size_t)l * Hh * Dd * DHd,
                                        dec_ca_wv + (size_t)l * Hh * Dd * DHd, BTqkv);
    gemm<float, false>(stream, Hb, BTqkv, nullptr, nullptr, QKV, Tt, Dd, Dd, QKVW);
    gemm<float, false>(stream, ENCFb, BTqkv + (size_t)Dd * Dd, nullptr, nullptr,
                       QKV + Dd, Tt, 2 * Dd, Dd, QKVW);
    fattn_k<<<attnG, blk, 0, stream>>>(QKV, AO);
    tcast_k<<<tcG((size_t)Dd * Dd), blk, 0, stream>>>(dec_ca_uo_w + (size_t)l * Dd * Dd, BTuo, Dd, Dd);
    gemm<float, false>(stream, AO, BTuo, dec_ca_uo_b + l * Dd, X, X, Tt, Dd, Dd, Dd);
    // ffn
    layernorm_k<<<Tt, blk, 0, stream>>>(X, dec_ln3_g + l * Dd, dec_ln3_b + l * Dd, Hb);
    tcast_k<<<tcG((size_t)Dd * FFf), blk, 0, stream>>>(dec_ff_w1 + (size_t)l * Dd * FFf, BTff1, Dd, FFf);
    gemm<ushort_t, true>(stream, Hb, BTff1, dec_ff_b1 + l * FFf, nullptr, Fb, Tt, FFf, Dd, FFf);
    tcast_k<<<tcG((size_t)FFf * Dd), blk, 0, stream>>>(dec_ff_w2 + (size_t)l * FFf * Dd, BTff2, FFf, Dd);
    gemm<float, false>(stream, Fb, BTff2, dec_ff_b2 + l * Dd, X, X, Tt, Dd, FFf, Dd);
  }
  layernorm_k<<<Tt, blk, 0, stream>>>(X, ln_dec_g, ln_dec_b, Hb);  // X dead after this

  tcast_k<<<tcG((size_t)Dd * Vv), blk, 0, stream>>>(head_w, BThead, Dd, Vv);
  gemm<float, false>(stream, Hb, BThead, head_b, nullptr, out, Tt, Vv, Dd, Vv);
}

// Round 5
// 900.053 us; speedup vs baseline: 8.7290x; 1.3793x over previous
//
#include <hip/hip_runtime.h>
#include <cstddef>
#include <cstdint>

constexpr int Vv = 32000, Dd = 512, Ss = 1024, Bb = 2, Hh = 8, DHd = 64, FFf = 2048;
constexpr int Tt = Bb * Ss;            // 2048 token rows
constexpr int QKVW = 3 * Dd;           // 1536 fused qkv width
constexpr float EPSf = 1e-5f;

typedef unsigned short ushort_t;
typedef short bf16x8 __attribute__((ext_vector_type(8)));
typedef short short4v __attribute__((ext_vector_type(4)));
typedef float f32x4 __attribute__((ext_vector_type(4)));

__device__ __forceinline__ ushort_t f2b(float f) {
  unsigned int u = __float_as_uint(f);
  unsigned int r = (u + 0x7FFFu + ((u >> 16) & 1u)) >> 16;   // round-to-nearest-even
  return (ushort_t)r;
}
__device__ __forceinline__ float bits2f(ushort_t u) {
  return __uint_as_float((unsigned int)u << 16);
}

__device__ __forceinline__ void st_out(float* p, float v) { *p = v; }
__device__ __forceinline__ void st_out(ushort_t* p, float v) { *p = f2b(v); }

__device__ __forceinline__ void gload_lds16(const void* g, void* l) {
  __builtin_amdgcn_global_load_lds(
      (const __attribute__((address_space(1))) unsigned int*)g,
      (__attribute__((address_space(3))) unsigned int*)l, 16, 0, 0);
}

// ---------------------------------------------------------------- embed + PE
__global__ __launch_bounds__(256) void embed_pe_k(const int* __restrict__ tok,
                                                  const float* __restrict__ emb,
                                                  float* __restrict__ X,
                                                  float* __restrict__ ENC) {
  int row = blockIdx.x;
  int s = row & (Ss - 1);
  int t = tok[row];
  const float* e = emb + (size_t)t * Dd;
  for (int d = threadIdx.x; d < Dd; d += 256) {
    int i = d >> 1;
    float den = expf(-(float)(2 * i) * (9.210340371976184f / 512.0f));
    float ang = (float)s * den;
    float pe = (d & 1) ? cosf(ang) : sinf(ang);
    float v = e[d] + pe;
    X[(size_t)row * Dd + d] = v;
    ENC[(size_t)row * Dd + d] = v;
  }
}

// ------------------------------------------- layernorm (f32 in -> bf16 out)
__global__ __launch_bounds__(256) void layernorm_k(const float* __restrict__ in,
                                                   const float* __restrict__ g,
                                                   const float* __restrict__ b,
                                                   ushort_t* __restrict__ out) {
  int row = blockIdx.x;
  const float* x = in + (size_t)row * Dd;
  int tid = threadIdx.x;
  float v0 = x[tid], v1 = x[tid + 256];
  float s = v0 + v1, ss = v0 * v0 + v1 * v1;
  for (int o = 32; o; o >>= 1) {
    s  += __shfl_down(s, o, 64);
    ss += __shfl_down(ss, o, 64);
  }
  __shared__ float rs[4], rss[4];
  int wid = tid >> 6, lane = tid & 63;
  if (lane == 0) { rs[wid] = s; rss[wid] = ss; }
  __syncthreads();
  __shared__ float mean_s, inv_s;
  if (tid == 0) {
    float a = rs[0] + rs[1] + rs[2] + rs[3];
    float c = rss[0] + rss[1] + rss[2] + rss[3];
    float m = a / Dd;
    float var = c / Dd - m * m;
    mean_s = m;
    inv_s = rsqrtf(var + EPSf);
  }
  __syncthreads();
  float m = mean_s, inv = inv_s;
  out[(size_t)row * Dd + tid]       = f2b((v0 - m) * inv * g[tid]       + b[tid]);
  out[(size_t)row * Dd + tid + 256] = f2b((v1 - m) * inv * g[tid + 256] + b[tid + 256]);
}

// ------------------- pack wq/wk/wv [H,D,DH] f32 -> BT bf16 [1536][512] (N,K)
__global__ __launch_bounds__(256) void qkvpack_k(const float* __restrict__ wq,
                                                 const float* __restrict__ wk,
                                                 const float* __restrict__ wv,
                                                 ushort_t* __restrict__ out) {
  int idx = blockIdx.x * 256 + threadIdx.x;      // over 1536*512
  if (idx >= QKVW * Dd) return;
  int n = idx >> 9;          // 0..1535
  int k = idx & 511;
  const float* src = (n < Dd) ? wq : (n < 2 * Dd ? wk : wv);
  int np = n & (Dd - 1);
  int h = np >> 6, e = np & 63;
  out[idx] = f2b(src[((size_t)h * Dd + k) * DHd + e]);
}

// --------------- LDS-tiled transpose-cast f32 [R][C] -> bf16 [C][R]
// grid (C/32, R/32), block 256. Coalesced on both sides.
__global__ __launch_bounds__(256) void tcast_k(const float* __restrict__ in,
                                               ushort_t* __restrict__ out,
                                               int R, int C) {
  __shared__ float t[32][33];
  int c0 = blockIdx.x * 32, r0 = blockIdx.y * 32;
  int tx = threadIdx.x & 31, ty = threadIdx.x >> 5;   // ty 0..7
#pragma unroll
  for (int i = 0; i < 4; i++)
    t[ty + i * 8][tx] = in[(size_t)(r0 + ty + i * 8) * C + c0 + tx];
  __syncthreads();
#pragma unroll
  for (int i = 0; i < 4; i++)
    out[(size_t)(c0 + ty + i * 8) * R + r0 + tx] = f2b(t[tx][ty + i * 8]);
}

// ---------------------------------------------------------------- MFMA GEMM
// C[M,N](ldc) = A[M,K]bf16 * BT[N,K]bf16^T  [+bias f32] [+resid f32] [relu]
// Templated tile BMxBN (64/128), BK=64, 4 waves (2x2), 1-D grid with
// bijective XCD-chunk swizzle (m204) + panel-major order for L2 reuse.
template <int BM, int BN, bool NMAJOR, typename OutT, bool RELU>
__global__ __launch_bounds__(256) void mfma_gemm_k(const ushort_t* __restrict__ A,
                                                   const ushort_t* __restrict__ BT,
                                                   const float* __restrict__ bias,
                                                   const float* __restrict__ resid,
                                                   OutT* __restrict__ C,
                                                   int M, int N, int K, int ldc,
                                                   int nbM, int nbN) {
  constexpr int FM = BM / 32, FN = BN / 32;   // 16x16 fragments per wave
  __shared__ __align__(16) ushort_t As[BM * 64];
  __shared__ __align__(16) ushort_t Bs[BN * 64];

  // XCD-chunk swizzle: contiguous l-range per XCD (assumes round-robin o%8)
  int o = blockIdx.x;
  int nwg = gridDim.x;
  int q = nwg >> 3, r = nwg & 7;
  int x = o & 7, i = o >> 3;
  int l = (x < r ? x * (q + 1) : r * (q + 1) + (x - r) * q) + i;
  int mb, nb;
  if (NMAJOR) { mb = l % nbM; nb = l / nbM; }   // consecutive l share B-panel
  else        { nb = l % nbN; mb = l / nbN; }   // consecutive l share A-panel
  int bm = mb * BM, bn = nb * BN;

  int tid = threadIdx.x;
  int lane = tid & 63, w = tid >> 6;
  int wr = w >> 1, wc = w & 1;
  f32x4 acc[FM][FN];
#pragma unroll
  for (int m = 0; m < FM; m++)
#pragma unroll
    for (int n = 0; n < FN; n++) acc[m][n] = (f32x4){0.f, 0.f, 0.f, 0.f};

  const ushort_t* aBase = A + (size_t)bm * K;
  const ushort_t* bBase = BT + (size_t)bn * K;
  int lr = lane & 15;
  int lk = (lane >> 4) * 8;

  for (int k0 = 0; k0 < K; k0 += 64) {
    __syncthreads();
#pragma unroll
    for (int it = 0; it < BM / 32; it++) {
      int cid = it * 256 + tid;
      int row = cid >> 3, c8 = cid & 7;
      gload_lds16(aBase + (size_t)row * K + k0 + c8 * 8, &As[cid * 8]);
    }
#pragma unroll
    for (int it = 0; it < BN / 32; it++) {
      int cid = it * 256 + tid;
      int row = cid >> 3, c8 = cid & 7;
      gload_lds16(bBase + (size_t)row * K + k0 + c8 * 8, &Bs[cid * 8]);
    }
    __syncthreads();
#pragma unroll
    for (int kk = 0; kk < 64; kk += 32) {
      bf16x8 af[FM], bfr[FN];
#pragma unroll
      for (int m = 0; m < FM; m++)
        af[m] = *(const bf16x8*)&As[(wr * (BM / 2) + m * 16 + lr) * 64 + kk + lk];
#pragma unroll
      for (int n = 0; n < FN; n++)
        bfr[n] = *(const bf16x8*)&Bs[(wc * (BN / 2) + n * 16 + lr) * 64 + kk + lk];
#pragma unroll
      for (int m = 0; m < FM; m++)
#pragma unroll
        for (int n = 0; n < FN; n++)
          acc[m][n] = __builtin_amdgcn_mfma_f32_16x16x32_bf16(af[m], bfr[n], acc[m][n], 0, 0, 0);
    }
  }

  int rowg = (lane >> 4) * 4;
#pragma unroll
  for (int m = 0; m < FM; m++) {
    int row0 = bm + wr * (BM / 2) + m * 16 + rowg;
#pragma unroll
    for (int n = 0; n < FN; n++) {
      int col = bn + wc * (BN / 2) + n * 16 + lr;
      float bv = bias ? bias[col] : 0.0f;
#pragma unroll
      for (int rr = 0; rr < 4; rr++) {
        int row = row0 + rr;
        float v = acc[m][n][rr] + bv;
        if (resid) v += resid[(size_t)row * ldc + col];
        if (RELU)  v = fmaxf(v, 0.0f);
        st_out(&C[(size_t)row * ldc + col], v);
      }
    }
  }
}

// --------------------------------------------------- fused flash attention
__global__ __launch_bounds__(256) void fattn_k(const float* __restrict__ QKV,
                                               ushort_t* __restrict__ AO) {
  int qt = blockIdx.x & 15;
  int h  = (blockIdx.x >> 4) & 7;
  int b  = blockIdx.x >> 7;
  int q0 = qt * 64;
  int tid = threadIdx.x;
  int lane = tid & 63, w = tid >> 6;
  int g = lane >> 4, c = lane & 15;

  __shared__ __align__(16) ushort_t Qh[64 * 64], Ql[64 * 64];
  __shared__ __align__(16) ushort_t Kh[64 * 64], Kl[64 * 64];
  __shared__ __align__(16) ushort_t VT[64 * 64];
  __shared__ __align__(16) ushort_t Ps[4][16 * 64];

  {
    int row = tid >> 2, c0 = (tid & 3) * 16;
    const float* qb = QKV + ((size_t)(b * Ss + q0 + row) * QKVW + h * DHd + c0);
#pragma unroll
    for (int i = 0; i < 4; i++) {
      float4 v = *(const float4*)(qb + i * 4);
      int col = c0 + i * 4;
      int sc = col ^ ((row & 7) << 3);
      ushort_t h0 = f2b(v.x), h1 = f2b(v.y), h2 = f2b(v.z), h3 = f2b(v.w);
      short4v hv = {(short)h0, (short)h1, (short)h2, (short)h3};
      short4v lv = {(short)f2b(v.x - bits2f(h0)), (short)f2b(v.y - bits2f(h1)),
                    (short)f2b(v.z - bits2f(h2)), (short)f2b(v.w - bits2f(h3))};
      *(short4v*)&Qh[row * 64 + sc] = hv;
      *(short4v*)&Ql[row * 64 + sc] = lv;
    }
  }

  f32x4 Oa[4];
#pragma unroll
  for (int n = 0; n < 4; n++) Oa[n] = (f32x4){0.f, 0.f, 0.f, 0.f};
  float mrow[4] = {-INFINITY, -INFINITY, -INFINITY, -INFINITY};
  float lrow[4] = {0.f, 0.f, 0.f, 0.f};

  int nkv = qt + 1;
  for (int it = 0; it < nkv; it++) {
    int t0 = it * 64;
    __syncthreads();
    {
      int row = tid >> 2, c0 = (tid & 3) * 16;
      const float* kb = QKV + ((size_t)(b * Ss + t0 + row) * QKVW + Dd + h * DHd + c0);
      const float* vb = kb + Dd;
#pragma unroll
      for (int i = 0; i < 4; i++) {
        float4 v = *(const float4*)(kb + i * 4);
        int col = c0 + i * 4;
        int sc = col ^ ((row & 7) << 3);
        ushort_t h0 = f2b(v.x), h1 = f2b(v.y), h2 = f2b(v.z), h3 = f2b(v.w);
        short4v hv = {(short)h0, (short)h1, (short)h2, (short)h3};
        short4v lv = {(short)f2b(v.x - bits2f(h0)), (short)f2b(v.y - bits2f(h1)),
                      (short)f2b(v.z - bits2f(h2)), (short)f2b(v.w - bits2f(h3))};
        *(short4v*)&Kh[row * 64 + sc] = hv;
        *(short4v*)&Kl[row * 64 + sc] = lv;
      }
#pragma unroll
      for (int i = 0; i < 4; i++) {
        float4 v = *(const float4*)(vb + i * 4);
        int e0 = c0 + i * 4;
        VT[(e0 + 0) * 64 + (row ^ (((e0 + 0) & 7) << 3))] = f2b(v.x);
        VT[(e0 + 1) * 64 + (row ^ (((e0 + 1) & 7) << 3))] = f2b(v.y);
        VT[(e0 + 2) * 64 + (row ^ (((e0 + 2) & 7) << 3))] = f2b(v.z);
        VT[(e0 + 3) * 64 + (row ^ (((e0 + 3) & 7) << 3))] = f2b(v.w);
      }
    }
    __syncthreads();

    int arow = w * 16 + c;
    int ksw0 = (0 + g * 8) ^ ((c & 7) << 3);
    int ksw1 = (32 + g * 8) ^ ((c & 7) << 3);
    bf16x8 qh0 = *(const bf16x8*)&Qh[arow * 64 + ksw0];
    bf16x8 qh1 = *(const bf16x8*)&Qh[arow * 64 + ksw1];
    bf16x8 ql0 = *(const bf16x8*)&Ql[arow * 64 + ksw0];
    bf16x8 ql1 = *(const bf16x8*)&Ql[arow * 64 + ksw1];

    f32x4 sfr[4];
#pragma unroll
    for (int n = 0; n < 4; n++) {
      int brow = n * 16 + c;
      bf16x8 kh0 = *(const bf16x8*)&Kh[brow * 64 + ksw0];
      bf16x8 kh1 = *(const bf16x8*)&Kh[brow * 64 + ksw1];
      bf16x8 kl0 = *(const bf16x8*)&Kl[brow * 64 + ksw0];
      bf16x8 kl1 = *(const bf16x8*)&Kl[brow * 64 + ksw1];
      f32x4 a = (f32x4){0.f, 0.f, 0.f, 0.f};
      a = __builtin_amdgcn_mfma_f32_16x16x32_bf16(qh0, kl0, a, 0, 0, 0);
      a = __builtin_amdgcn_mfma_f32_16x16x32_bf16(qh1, kl1, a, 0, 0, 0);
      a = __builtin_amdgcn_mfma_f32_16x16x32_bf16(ql0, kh0, a, 0, 0, 0);
      a = __builtin_amdgcn_mfma_f32_16x16x32_bf16(ql1, kh1, a, 0, 0, 0);
      a = __builtin_amdgcn_mfma_f32_16x16x32_bf16(qh0, kh0, a, 0, 0, 0);
      a = __builtin_amdgcn_mfma_f32_16x16x32_bf16(qh1, kh1, a, 0, 0, 0);
      sfr[n] = a;
    }

#pragma unroll
    for (int n = 0; n < 4; n++) {
#pragma unroll
      for (int rr = 0; rr < 4; rr++) sfr[n][rr] *= 8.0f;
    }
    if (t0 == q0) {
#pragma unroll
      for (int n = 0; n < 4; n++) {
        int t = t0 + n * 16 + c;
#pragma unroll
        for (int rr = 0; rr < 4; rr++) {
          int s = q0 + w * 16 + g * 4 + rr;
          if (t > s) sfr[n][rr] = -INFINITY;
        }
      }
    }

    float pnew[4], scold[4];
#pragma unroll
    for (int rr = 0; rr < 4; rr++) {
      float tm = fmaxf(fmaxf(sfr[0][rr], sfr[1][rr]), fmaxf(sfr[2][rr], sfr[3][rr]));
      tm = fmaxf(tm, __shfl_xor(tm, 1));
      tm = fmaxf(tm, __shfl_xor(tm, 2));
      tm = fmaxf(tm, __shfl_xor(tm, 4));
      tm = fmaxf(tm, __shfl_xor(tm, 8));
      float mn = fmaxf(mrow[rr], tm);
      scold[rr] = __expf(mrow[rr] - mn);
      mrow[rr] = mn;
      pnew[rr] = mn;
    }
#pragma unroll
    for (int n = 0; n < 4; n++) {
#pragma unroll
      for (int rr = 0; rr < 4; rr++) sfr[n][rr] = __expf(sfr[n][rr] - pnew[rr]);
    }
#pragma unroll
    for (int rr = 0; rr < 4; rr++) {
      float s = sfr[0][rr] + sfr[1][rr] + sfr[2][rr] + sfr[3][rr];
      s += __shfl_xor(s, 1);
      s += __shfl_xor(s, 2);
      s += __shfl_xor(s, 4);
      s += __shfl_xor(s, 8);
      lrow[rr] = lrow[rr] * scold[rr] + s;
    }

#pragma unroll
    for (int n = 0; n < 4; n++) {
#pragma unroll
      for (int rr = 0; rr < 4; rr++) {
        int prow = g * 4 + rr;
        Ps[w][prow * 64 + ((n * 16 + c) ^ ((prow & 7) << 3))] = f2b(sfr[n][rr]);
      }
    }

#pragma unroll
    for (int n = 0; n < 4; n++) {
#pragma unroll
      for (int rr = 0; rr < 4; rr++) Oa[n][rr] *= scold[rr];
    }

    bf16x8 pa0 = *(const bf16x8*)&Ps[w][c * 64 + ksw0];
    bf16x8 pa1 = *(const bf16x8*)&Ps[w][c * 64 + ksw1];
#pragma unroll
    for (int n = 0; n < 4; n++) {
      int vrow = n * 16 + c;
      bf16x8 v0 = *(const bf16x8*)&VT[vrow * 64 + ksw0];
      bf16x8 v1 = *(const bf16x8*)&VT[vrow * 64 + ksw1];
      Oa[n] = __builtin_amdgcn_mfma_f32_16x16x32_bf16(pa0, v0, Oa[n], 0, 0, 0);
      Oa[n] = __builtin_amdgcn_mfma_f32_16x16x32_bf16(pa1, v1, Oa[n], 0, 0, 0);
    }
  }

#pragma unroll
  for (int rr = 0; rr < 4; rr++) {
    float inv = 1.0f / lrow[rr];
    int row = b * Ss + q0 + w * 16 + g * 4 + rr;
#pragma unroll
    for (int n = 0; n < 4; n++) {
      AO[(size_t)row * Dd + h * DHd + n * 16 + c] = f2b(Oa[n][rr] * inv);
    }
  }
}

// ---------------------------------------------------------------- host side
template <int BM, int BN, bool NMAJOR, typename OutT, bool RELU>
static void gemm(hipStream_t st, const ushort_t* A, const ushort_t* BT, const float* bias,
                 const float* resid, OutT* C, int M, int N, int K, int ldc) {
  int nbM = M / BM, nbN = N / BN;
  dim3 g(nbM * nbN), blk(256);
  mfma_gemm_k<BM, BN, NMAJOR, OutT, RELU><<<g, blk, 0, st>>>(A, BT, bias, resid, C, M, N, K, ldc, nbM, nbN);
}

extern "C" void kernel_launch(void* const* d_in, const int* in_sizes, int n_in,
                              void* d_out, int out_size, void* d_ws, size_t ws_size,
                              hipStream_t stream) {
  const int*   tokens    = (const int*)d_in[0];
  const float* emb       = (const float*)d_in[1];
  const float* enc_wq    = (const float*)d_in[2];
  const float* enc_wk    = (const float*)d_in[3];
  const float* enc_wv    = (const float*)d_in[4];
  const float* enc_uo_w  = (const float*)d_in[5];
  const float* enc_uo_b  = (const float*)d_in[6];
  const float* enc_ln1_g = (const float*)d_in[7];
  const float* enc_ln1_b = (const float*)d_in[8];
  const float* enc_ln2_g = (const float*)d_in[9];
  const float* enc_ln2_b = (const float*)d_in[10];
  const float* enc_ff_w1 = (const float*)d_in[11];
  const float* enc_ff_b1 = (const float*)d_in[12];
  const float* enc_ff_w2 = (const float*)d_in[13];
  const float* enc_ff_b2 = (const float*)d_in[14];
  const float* dec_sa_wq = (const float*)d_in[15];
  const float* dec_sa_wk = (const float*)d_in[16];
  const float* dec_sa_wv = (const float*)d_in[17];
  const float* dec_sa_uo_w = (const float*)d_in[18];
  const float* dec_sa_uo_b = (const float*)d_in[19];
  const float* dec_ca_wq = (const float*)d_in[20];
  const float* dec_ca_wk = (const float*)d_in[21];
  const float* dec_ca_wv = (const float*)d_in[22];
  const float* dec_ca_uo_w = (const float*)d_in[23];
  const float* dec_ca_uo_b = (const float*)d_in[24];
  const float* dec_ln1_g = (const float*)d_in[25];
  const float* dec_ln1_b = (const float*)d_in[26];
  const float* dec_ln2_g = (const float*)d_in[27];
  const float* dec_ln2_b = (const float*)d_in[28];
  const float* dec_ln3_g = (const float*)d_in[29];
  const float* dec_ln3_b = (const float*)d_in[30];
  const float* dec_ff_w1 = (const float*)d_in[31];
  const float* dec_ff_b1 = (const float*)d_in[32];
  const float* dec_ff_w2 = (const float*)d_in[33];
  const float* dec_ff_b2 = (const float*)d_in[34];
  const float* ln_enc_g  = (const float*)d_in[35];
  const float* ln_enc_b  = (const float*)d_in[36];
  const float* ln_dec_g  = (const float*)d_in[37];
  const float* ln_dec_b  = (const float*)d_in[38];
  const float* head_w    = (const float*)d_in[39];
  const float* head_b    = (const float*)d_in[40];
  float* out = (float*)d_out;

  char* ws = (char*)d_ws;
  size_t off = 0;
  auto alloc = [&](size_t bytes) {
    void* p = ws + off;
    off += (bytes + 255) & ~(size_t)255;
    return p;
  };
  ushort_t* Hb    = (ushort_t*)alloc((size_t)Tt * Dd * 2);
  ushort_t* ENCFb = (ushort_t*)alloc((size_t)Tt * Dd * 2);
  float*    X     = (float*)alloc((size_t)Tt * Dd * 4);
  float*    ENC   = (float*)alloc((size_t)Tt * Dd * 4);
  float*    QKV   = (float*)alloc((size_t)Tt * QKVW * 4);
  ushort_t* AO    = (ushort_t*)alloc((size_t)Tt * Dd * 2);
  ushort_t* Fb    = (ushort_t*)alloc((size_t)Tt * FFf * 2);
  ushort_t* BTqkv = (ushort_t*)alloc((size_t)QKVW * Dd * 2);
  ushort_t* BTuo  = (ushort_t*)alloc((size_t)Dd * Dd * 2);
  ushort_t* BTff1 = (ushort_t*)alloc((size_t)FFf * Dd * 2);
  ushort_t* BTff2 = (ushort_t*)alloc((size_t)Dd * FFf * 2);
  ushort_t* BThead = (ushort_t*)X;   // head BT reuses dead X.. region at tail

  dim3 blk(256);
  dim3 qkvG((QKVW * Dd + 255) / 256);
  dim3 attnG(Bb * Hh * (Ss / 64));   // 256 blocks
  auto tcG = [](int R, int C) { return dim3(C / 32, R / 32); };

  embed_pe_k<<<Tt, blk, 0, stream>>>(tokens, emb, X, ENC);

  // -------- encoder --------
  for (int l = 0; l < 2; l++) {
    layernorm_k<<<Tt, blk, 0, stream>>>(ENC, enc_ln1_g + l * Dd, enc_ln1_b + l * Dd, Hb);
    qkvpack_k<<<qkvG, blk, 0, stream>>>(enc_wq + (size_t)l * Hh * Dd * DHd,
                                        enc_wk + (size_t)l * Hh * Dd * DHd,
                                        enc_wv + (size_t)l * Hh * Dd * DHd, BTqkv);
    gemm<64, 128, true, float, false>(stream, Hb, BTqkv, nullptr, nullptr, QKV, Tt, QKVW, Dd, QKVW);
    fattn_k<<<attnG, blk, 0, stream>>>(QKV, AO);
    tcast_k<<<tcG(Dd, Dd), blk, 0, stream>>>(enc_uo_w + (size_t)l * Dd * Dd, BTuo, Dd, Dd);
    gemm<64, 64, true, float, false>(stream, AO, BTuo, enc_uo_b + l * Dd, ENC, ENC, Tt, Dd, Dd, Dd);
    layernorm_k<<<Tt, blk, 0, stream>>>(ENC, enc_ln2_g + l * Dd, enc_ln2_b + l * Dd, Hb);
    tcast_k<<<tcG(Dd, FFf), blk, 0, stream>>>(enc_ff_w1 + (size_t)l * Dd * FFf, BTff1, Dd, FFf);
    gemm<128, 128, true, ushort_t, true>(stream, Hb, BTff1, enc_ff_b1 + l * FFf, nullptr, Fb, Tt, FFf, Dd, FFf);
    tcast_k<<<tcG(FFf, Dd), blk, 0, stream>>>(enc_ff_w2 + (size_t)l * FFf * Dd, BTff2, FFf, Dd);
    gemm<64, 64, false, float, false>(stream, Fb, BTff2, enc_ff_b2 + l * Dd, ENC, ENC, Tt, Dd, FFf, Dd);
  }
  layernorm_k<<<Tt, blk, 0, stream>>>(ENC, ln_enc_g, ln_enc_b, ENCFb);

  // -------- decoder --------
  for (int l = 0; l < 2; l++) {
    layernorm_k<<<Tt, blk, 0, stream>>>(X, dec_ln1_g + l * Dd, dec_ln1_b + l * Dd, Hb);
    qkvpack_k<<<qkvG, blk, 0, stream>>>(dec_sa_wq + (size_t)l * Hh * Dd * DHd,
                                        dec_sa_wk + (size_t)l * Hh * Dd * DHd,
                                        dec_sa_wv + (size_t)l * Hh * Dd * DHd, BTqkv);
    gemm<64, 128, true, float, false>(stream, Hb, BTqkv, nullptr, nullptr, QKV, Tt, QKVW, Dd, QKVW);
    fattn_k<<<attnG, blk, 0, stream>>>(QKV, AO);
    tcast_k<<<tcG(Dd, Dd), blk, 0, stream>>>(dec_sa_uo_w + (size_t)l * Dd * Dd, BTuo, Dd, Dd);
    gemm<64, 64, true, float, false>(stream, AO, BTuo, dec_sa_uo_b + l * Dd, X, X, Tt, Dd, Dd, Dd);
    // cross-attention: Q from LN(x), K/V from ENCFb (faithful causal mask)
    layernorm_k<<<Tt, blk, 0, stream>>>(X, dec_ln2_g + l * Dd, dec_ln2_b + l * Dd, Hb);
    qkvpack_k<<<qkvG, blk, 0, stream>>>(dec_ca_wq + (size_t)l * Hh * Dd * DHd,
                                        dec_ca_wk + (size_t)l * Hh * Dd * DHd,
                                        dec_ca_wv + (size_t)l * Hh * Dd * DHd, BTqkv);
    gemm<64, 64, true, float, false>(stream, Hb, BTqkv, nullptr, nullptr, QKV, Tt, Dd, Dd, QKVW);
    gemm<64, 128, true, float, false>(stream, ENCFb, BTqkv + (size_t)Dd * Dd, nullptr, nullptr,
                                      QKV + Dd, Tt, 2 * Dd, Dd, QKVW);
    fattn_k<<<attnG, blk, 0, stream>>>(QKV, AO);
    tcast_k<<<tcG(Dd, Dd), blk, 0, stream>>>(dec_ca_uo_w + (size_t)l * Dd * Dd, BTuo, Dd, Dd);
    gemm<64, 64, true, float, false>(stream, AO, BTuo, dec_ca_uo_b + l * Dd, X, X, Tt, Dd, Dd, Dd);
    // ffn
    layernorm_k<<<Tt, blk, 0, stream>>>(X, dec_ln3_g + l * Dd, dec_ln3_b + l * Dd, Hb);
    tcast_k<<<tcG(Dd, FFf), blk, 0, stream>>>(dec_ff_w1 + (size_t)l * Dd * FFf, BTff1, Dd, FFf);
    gemm<128, 128, true, ushort_t, true>(stream, Hb, BTff1, dec_ff_b1 + l * FFf, nullptr, Fb, Tt, FFf, Dd, FFf);
    tcast_k<<<tcG(FFf, Dd), blk, 0, stream>>>(dec_ff_w2 + (size_t)l * FFf * Dd, BTff2, FFf, Dd);
    gemm<64, 64, false, float, false>(stream, Fb, BTff2, dec_ff_b2 + l * Dd, X, X, Tt, Dd, FFf, Dd);
  }
  layernorm_k<<<Tt, blk, 0, stream>>>(X, ln_dec_g, ln_dec_b, Hb);  // X dead after this

  tcast_k<<<tcG(Dd, Vv), blk, 0, stream>>>(head_w, BThead, Dd, Vv);
  gemm<128, 128, true, float, false>(stream, Hb, BThead, head_b, nullptr, out, Tt, Vv, Dd, Vv);
}

// Round 6
// 890.389 us; speedup vs baseline: 8.8238x; 1.0109x over previous
//
#include <hip/hip_runtime.h>
#include <cstddef>
#include <cstdint>

constexpr int Vv = 32000, Dd = 512, Ss = 1024, Bb = 2, Hh = 8, DHd = 64, FFf = 2048;
constexpr int Tt = Bb * Ss;            // 2048 token rows
constexpr int QKVW = 3 * Dd;           // 1536 fused qkv width
constexpr float EPSf = 1e-5f;

typedef unsigned short ushort_t;
typedef short bf16x8 __attribute__((ext_vector_type(8)));
typedef short short4v __attribute__((ext_vector_type(4)));
typedef float f32x4 __attribute__((ext_vector_type(4)));

__device__ __forceinline__ ushort_t f2b(float f) {
  unsigned int u = __float_as_uint(f);
  unsigned int r = (u + 0x7FFFu + ((u >> 16) & 1u)) >> 16;   // round-to-nearest-even
  return (ushort_t)r;
}
__device__ __forceinline__ float bits2f(ushort_t u) {
  return __uint_as_float((unsigned int)u << 16);
}

__device__ __forceinline__ void st_out(float* p, float v) { *p = v; }
__device__ __forceinline__ void st_out(ushort_t* p, float v) { *p = f2b(v); }

__device__ __forceinline__ void gload_lds16(const void* g, void* l) {
  __builtin_amdgcn_global_load_lds(
      (const __attribute__((address_space(1))) unsigned int*)g,
      (__attribute__((address_space(3))) unsigned int*)l, 16, 0, 0);
}

// ---------------------------------------------------------------- embed + PE
__global__ __launch_bounds__(256) void embed_pe_k(const int* __restrict__ tok,
                                                  const float* __restrict__ emb,
                                                  float* __restrict__ X,
                                                  float* __restrict__ ENC) {
  int row = blockIdx.x;
  int s = row & (Ss - 1);
  int t = tok[row];
  const float* e = emb + (size_t)t * Dd;
  for (int d = threadIdx.x; d < Dd; d += 256) {
    int i = d >> 1;
    float den = expf(-(float)(2 * i) * (9.210340371976184f / 512.0f));
    float ang = (float)s * den;
    float pe = (d & 1) ? cosf(ang) : sinf(ang);
    float v = e[d] + pe;
    X[(size_t)row * Dd + d] = v;
    ENC[(size_t)row * Dd + d] = v;
  }
}

// ------------------------------------------- layernorm (f32 in -> bf16 out)
__global__ __launch_bounds__(256) void layernorm_k(const float* __restrict__ in,
                                                   const float* __restrict__ g,
                                                   const float* __restrict__ b,
                                                   ushort_t* __restrict__ out) {
  int row = blockIdx.x;
  const float* x = in + (size_t)row * Dd;
  int tid = threadIdx.x;
  float v0 = x[tid], v1 = x[tid + 256];
  float s = v0 + v1, ss = v0 * v0 + v1 * v1;
  for (int o = 32; o; o >>= 1) {
    s  += __shfl_down(s, o, 64);
    ss += __shfl_down(ss, o, 64);
  }
  __shared__ float rs[4], rss[4];
  int wid = tid >> 6, lane = tid & 63;
  if (lane == 0) { rs[wid] = s; rss[wid] = ss; }
  __syncthreads();
  __shared__ float mean_s, inv_s;
  if (tid == 0) {
    float a = rs[0] + rs[1] + rs[2] + rs[3];
    float c = rss[0] + rss[1] + rss[2] + rss[3];
    float m = a / Dd;
    float var = c / Dd - m * m;
    mean_s = m;
    inv_s = rsqrtf(var + EPSf);
  }
  __syncthreads();
  float m = mean_s, inv = inv_s;
  out[(size_t)row * Dd + tid]       = f2b((v0 - m) * inv * g[tid]       + b[tid]);
  out[(size_t)row * Dd + tid + 256] = f2b((v1 - m) * inv * g[tid + 256] + b[tid + 256]);
}

// ------------------- pack wq/wk/wv [H,D,DH] f32 -> BT bf16 [1536][512] (N,K)
__global__ __launch_bounds__(256) void qkvpack_k(const float* __restrict__ wq,
                                                 const float* __restrict__ wk,
                                                 const float* __restrict__ wv,
                                                 ushort_t* __restrict__ out) {
  int idx = blockIdx.x * 256 + threadIdx.x;      // over 1536*512
  if (idx >= QKVW * Dd) return;
  int n = idx >> 9;          // 0..1535
  int k = idx & 511;
  const float* src = (n < Dd) ? wq : (n < 2 * Dd ? wk : wv);
  int np = n & (Dd - 1);
  int h = np >> 6, e = np & 63;
  out[idx] = f2b(src[((size_t)h * Dd + k) * DHd + e]);
}

// --------------- LDS-tiled transpose-cast f32 [R][C] -> bf16 [C][R]
__global__ __launch_bounds__(256) void tcast_k(const float* __restrict__ in,
                                               ushort_t* __restrict__ out,
                                               int R, int C) {
  __shared__ float t[32][33];
  int c0 = blockIdx.x * 32, r0 = blockIdx.y * 32;
  int tx = threadIdx.x & 31, ty = threadIdx.x >> 5;   // ty 0..7
#pragma unroll
  for (int i = 0; i < 4; i++)
    t[ty + i * 8][tx] = in[(size_t)(r0 + ty + i * 8) * C + c0 + tx];
  __syncthreads();
#pragma unroll
  for (int i = 0; i < 4; i++)
    out[(size_t)(c0 + ty + i * 8) * R + r0 + tx] = f2b(t[tx][ty + i * 8]);
}

// ---------------------------------------------------------------- MFMA GEMM
// C[M,N](ldc) = A[M,K]bf16 * BT[N,K]bf16^T  [+bias f32] [+resid f32] [relu]
// Double-buffered prefetch (T3 min-2-phase: stage t+1 BEFORE compute t, one
// barrier/tile whose implicit vmcnt(0) lands after the MFMAs). LDS holds a
// column-XOR-swizzled image via pre-swizzled GLOBAL source (rule #21):
// slot (row,c8) holds source col-group c8^(row&7); reads apply the same XOR.
template <int BM, int BN, bool NMAJOR, typename OutT, bool RELU>
__global__ __launch_bounds__(256) void mfma_gemm_k(const ushort_t* __restrict__ A,
                                                   const ushort_t* __restrict__ BT,
                                                   const float* __restrict__ bias,
                                                   const float* __restrict__ resid,
                                                   OutT* __restrict__ C,
                                                   int M, int N, int K, int ldc,
                                                   int nbM, int nbN) {
  constexpr int FM = BM / 32, FN = BN / 32;   // 16x16 fragments per wave
  __shared__ __align__(16) ushort_t As[2][BM * 64];
  __shared__ __align__(16) ushort_t Bs[2][BN * 64];

  // bijective XCD-chunk swizzle (m204)
  int o = blockIdx.x;
  int nwg = gridDim.x;
  int q = nwg >> 3, r = nwg & 7;
  int x = o & 7, i = o >> 3;
  int l = (x < r ? x * (q + 1) : r * (q + 1) + (x - r) * q) + i;
  int mb, nb;
  if (NMAJOR) { mb = l % nbM; nb = l / nbM; }
  else        { nb = l % nbN; mb = l / nbN; }
  int bm = mb * BM, bn = nb * BN;

  int tid = threadIdx.x;
  int lane = tid & 63, w = tid >> 6;
  int wr = w >> 1, wc = w & 1;
  f32x4 acc[FM][FN];
#pragma unroll
  for (int m = 0; m < FM; m++)
#pragma unroll
    for (int n = 0; n < FN; n++) acc[m][n] = (f32x4){0.f, 0.f, 0.f, 0.f};

  const ushort_t* aBase = A + (size_t)bm * K;
  const ushort_t* bBase = BT + (size_t)bn * K;
  int lr = lane & 15;
  int lk = (lane >> 4) * 8;

  auto stage = [&](int buf, int k0) {
#pragma unroll
    for (int it = 0; it < BM / 32; it++) {
      int cid = it * 256 + tid;
      int row = cid >> 3, c8 = cid & 7;
      int sc8 = c8 ^ (row & 7);                      // inverse-swizzled source
      gload_lds16(aBase + (size_t)row * K + k0 + sc8 * 8, &As[buf][cid * 8]);
    }
#pragma unroll
    for (int it = 0; it < BN / 32; it++) {
      int cid = it * 256 + tid;
      int row = cid >> 3, c8 = cid & 7;
      int sc8 = c8 ^ (row & 7);
      gload_lds16(bBase + (size_t)row * K + k0 + sc8 * 8, &Bs[buf][cid * 8]);
    }
  };

  stage(0, 0);
  __syncthreads();                       // implicit vmcnt(0): buf0 ready
  int nt = K >> 6;
  for (int t = 0; t < nt; t++) {
    int cur = t & 1;
    if (t + 1 < nt) stage(cur ^ 1, (t + 1) << 6);   // overlap with compute
#pragma unroll
    for (int kk = 0; kk < 64; kk += 32) {
      bf16x8 af[FM], bfr[FN];
#pragma unroll
      for (int m = 0; m < FM; m++) {
        int row = wr * (BM / 2) + m * 16 + lr;
        af[m] = *(const bf16x8*)&As[cur][row * 64 + ((kk + lk) ^ ((row & 7) << 3))];
      }
#pragma unroll
      for (int n = 0; n < FN; n++) {
        int row = wc * (BN / 2) + n * 16 + lr;
        bfr[n] = *(const bf16x8*)&Bs[cur][row * 64 + ((kk + lk) ^ ((row & 7) << 3))];
      }
#pragma unroll
      for (int m = 0; m < FM; m++)
#pragma unroll
        for (int n = 0; n < FN; n++)
          acc[m][n] = __builtin_amdgcn_mfma_f32_16x16x32_bf16(af[m], bfr[n], acc[m][n], 0, 0, 0);
    }
    __syncthreads();   // drains prefetch (next buf ready) + guards reuse of cur
  }

  int rowg = (lane >> 4) * 4;
#pragma unroll
  for (int m = 0; m < FM; m++) {
    int row0 = bm + wr * (BM / 2) + m * 16 + rowg;
#pragma unroll
    for (int n = 0; n < FN; n++) {
      int col = bn + wc * (BN / 2) + n * 16 + lr;
      float bv = bias ? bias[col] : 0.0f;
#pragma unroll
      for (int rr = 0; rr < 4; rr++) {
        int row = row0 + rr;
        float v = acc[m][n][rr] + bv;
        if (resid) v += resid[(size_t)row * ldc + col];
        if (RELU)  v = fmaxf(v, 0.0f);
        st_out(&C[(size_t)row * ldc + col], v);
      }
    }
  }
}

// --------------------------------------------------- fused flash attention
// 32 q-rows per block, 2 waves (wave w = rows w*16..+15), grid 512 with
// balanced qt order (desc first half, asc second) so per-CU work ~constant.
__global__ __launch_bounds__(128) void fattn_k(const float* __restrict__ QKV,
                                               ushort_t* __restrict__ AO) {
  int bid = blockIdx.x;
  int i4 = bid >> 4;                         // 0..31
  int qt = (i4 < 16) ? (31 - i4) : (i4 - 16);
  int h  = bid & 7;
  int b  = (bid >> 3) & 1;
  int q0 = qt * 32;
  int tid = threadIdx.x;                     // 0..127
  int lane = tid & 63, w = tid >> 6;         // w in {0,1}
  int g = lane >> 4, c = lane & 15;

  __shared__ __align__(16) ushort_t Qh[32 * 64], Ql[32 * 64];
  __shared__ __align__(16) ushort_t Kh[64 * 64], Kl[64 * 64];
  __shared__ __align__(16) ushort_t VT[64 * 64];
  __shared__ __align__(16) ushort_t Ps[2][16 * 64];

  // ---- stage Q (hi/lo, swizzled): row = tid>>2 (0..31), cols (tid&3)*16..+16
  {
    int row = tid >> 2, c0 = (tid & 3) * 16;
    const float* qb = QKV + ((size_t)(b * Ss + q0 + row) * QKVW + h * DHd + c0);
#pragma unroll
    for (int ii = 0; ii < 4; ii++) {
      float4 v = *(const float4*)(qb + ii * 4);
      int col = c0 + ii * 4;
      int sc = col ^ ((row & 7) << 3);
      ushort_t h0 = f2b(v.x), h1 = f2b(v.y), h2 = f2b(v.z), h3 = f2b(v.w);
      short4v hv = {(short)h0, (short)h1, (short)h2, (short)h3};
      short4v lv = {(short)f2b(v.x - bits2f(h0)), (short)f2b(v.y - bits2f(h1)),
                    (short)f2b(v.z - bits2f(h2)), (short)f2b(v.w - bits2f(h3))};
      *(short4v*)&Qh[row * 64 + sc] = hv;
      *(short4v*)&Ql[row * 64 + sc] = lv;
    }
  }

  f32x4 Oa[4];
#pragma unroll
  for (int n = 0; n < 4; n++) Oa[n] = (f32x4){0.f, 0.f, 0.f, 0.f};
  float mrow[4] = {-INFINITY, -INFINITY, -INFINITY, -INFINITY};
  float lrow[4] = {0.f, 0.f, 0.f, 0.f};

  int nkv = (qt >> 1) + 1;
  for (int it = 0; it < nkv; it++) {
    int t0 = it * 64;
    __syncthreads();
    // ---- stage K hi/lo + V^T: row = tid>>1 (0..63), cols (tid&1)*32..+32
    {
      int row = tid >> 1, c0 = (tid & 1) * 32;
      const float* kb = QKV + ((size_t)(b * Ss + t0 + row) * QKVW + Dd + h * DHd + c0);
      const float* vb = kb + Dd;
#pragma unroll
      for (int ii = 0; ii < 8; ii++) {
        float4 v = *(const float4*)(kb + ii * 4);
        int col = c0 + ii * 4;
        int sc = col ^ ((row & 7) << 3);
        ushort_t h0 = f2b(v.x), h1 = f2b(v.y), h2 = f2b(v.z), h3 = f2b(v.w);
        short4v hv = {(short)h0, (short)h1, (short)h2, (short)h3};
        short4v lv = {(short)f2b(v.x - bits2f(h0)), (short)f2b(v.y - bits2f(h1)),
                      (short)f2b(v.z - bits2f(h2)), (short)f2b(v.w - bits2f(h3))};
        *(short4v*)&Kh[row * 64 + sc] = hv;
        *(short4v*)&Kl[row * 64 + sc] = lv;
      }
#pragma unroll
      for (int ii = 0; ii < 8; ii++) {
        float4 v = *(const float4*)(vb + ii * 4);
        int e0 = c0 + ii * 4;
        VT[(e0 + 0) * 64 + (row ^ (((e0 + 0) & 7) << 3))] = f2b(v.x);
        VT[(e0 + 1) * 64 + (row ^ (((e0 + 1) & 7) << 3))] = f2b(v.y);
        VT[(e0 + 2) * 64 + (row ^ (((e0 + 2) & 7) << 3))] = f2b(v.z);
        VT[(e0 + 3) * 64 + (row ^ (((e0 + 3) & 7) << 3))] = f2b(v.w);
      }
    }
    __syncthreads();

    int arow = w * 16 + c;
    int ksw0 = (0 + g * 8) ^ ((c & 7) << 3);
    int ksw1 = (32 + g * 8) ^ ((c & 7) << 3);
    bf16x8 qh0 = *(const bf16x8*)&Qh[arow * 64 + ksw0];
    bf16x8 qh1 = *(const bf16x8*)&Qh[arow * 64 + ksw1];
    bf16x8 ql0 = *(const bf16x8*)&Ql[arow * 64 + ksw0];
    bf16x8 ql1 = *(const bf16x8*)&Ql[arow * 64 + ksw1];

    f32x4 sfr[4];
#pragma unroll
    for (int n = 0; n < 4; n++) {
      int brow = n * 16 + c;
      bf16x8 kh0 = *(const bf16x8*)&Kh[brow * 64 + ksw0];
      bf16x8 kh1 = *(const bf16x8*)&Kh[brow * 64 + ksw1];
      bf16x8 kl0 = *(const bf16x8*)&Kl[brow * 64 + ksw0];
      bf16x8 kl1 = *(const bf16x8*)&Kl[brow * 64 + ksw1];
      f32x4 a = (f32x4){0.f, 0.f, 0.f, 0.f};
      a = __builtin_amdgcn_mfma_f32_16x16x32_bf16(qh0, kl0, a, 0, 0, 0);
      a = __builtin_amdgcn_mfma_f32_16x16x32_bf16(qh1, kl1, a, 0, 0, 0);
      a = __builtin_amdgcn_mfma_f32_16x16x32_bf16(ql0, kh0, a, 0, 0, 0);
      a = __builtin_amdgcn_mfma_f32_16x16x32_bf16(ql1, kh1, a, 0, 0, 0);
      a = __builtin_amdgcn_mfma_f32_16x16x32_bf16(qh0, kh0, a, 0, 0, 0);
      a = __builtin_amdgcn_mfma_f32_16x16x32_bf16(qh1, kh1, a, 0, 0, 0);
      sfr[n] = a;
    }

#pragma unroll
    for (int n = 0; n < 4; n++) {
#pragma unroll
      for (int rr = 0; rr < 4; rr++) sfr[n][rr] *= 8.0f;
    }
    if (it == nkv - 1) {   // only the last tile can cross the diagonal
#pragma unroll
      for (int n = 0; n < 4; n++) {
        int t = t0 + n * 16 + c;
#pragma unroll
        for (int rr = 0; rr < 4; rr++) {
          int s = q0 + w * 16 + g * 4 + rr;
          if (t > s) sfr[n][rr] = -INFINITY;
        }
      }
    }

    float pnew[4], scold[4];
#pragma unroll
    for (int rr = 0; rr < 4; rr++) {
      float tm = fmaxf(fmaxf(sfr[0][rr], sfr[1][rr]), fmaxf(sfr[2][rr], sfr[3][rr]));
      tm = fmaxf(tm, __shfl_xor(tm, 1));
      tm = fmaxf(tm, __shfl_xor(tm, 2));
      tm = fmaxf(tm, __shfl_xor(tm, 4));
      tm = fmaxf(tm, __shfl_xor(tm, 8));
      float mn = fmaxf(mrow[rr], tm);
      scold[rr] = __expf(mrow[rr] - mn);
      mrow[rr] = mn;
      pnew[rr] = mn;
    }
#pragma unroll
    for (int n = 0; n < 4; n++) {
#pragma unroll
      for (int rr = 0; rr < 4; rr++) sfr[n][rr] = __expf(sfr[n][rr] - pnew[rr]);
    }
#pragma unroll
    for (int rr = 0; rr < 4; rr++) {
      float s = sfr[0][rr] + sfr[1][rr] + sfr[2][rr] + sfr[3][rr];
      s += __shfl_xor(s, 1);
      s += __shfl_xor(s, 2);
      s += __shfl_xor(s, 4);
      s += __shfl_xor(s, 8);
      lrow[rr] = lrow[rr] * scold[rr] + s;
    }

#pragma unroll
    for (int n = 0; n < 4; n++) {
#pragma unroll
      for (int rr = 0; rr < 4; rr++) {
        int prow = g * 4 + rr;
        Ps[w][prow * 64 + ((n * 16 + c) ^ ((prow & 7) << 3))] = f2b(sfr[n][rr]);
      }
    }

#pragma unroll
    for (int n = 0; n < 4; n++) {
#pragma unroll
      for (int rr = 0; rr < 4; rr++) Oa[n][rr] *= scold[rr];
    }

    bf16x8 pa0 = *(const bf16x8*)&Ps[w][c * 64 + ksw0];
    bf16x8 pa1 = *(const bf16x8*)&Ps[w][c * 64 + ksw1];
#pragma unroll
    for (int n = 0; n < 4; n++) {
      int vrow = n * 16 + c;
      bf16x8 v0 = *(const bf16x8*)&VT[vrow * 64 + ksw0];
      bf16x8 v1 = *(const bf16x8*)&VT[vrow * 64 + ksw1];
      Oa[n] = __builtin_amdgcn_mfma_f32_16x16x32_bf16(pa0, v0, Oa[n], 0, 0, 0);
      Oa[n] = __builtin_amdgcn_mfma_f32_16x16x32_bf16(pa1, v1, Oa[n], 0, 0, 0);
    }
  }

#pragma unroll
  for (int rr = 0; rr < 4; rr++) {
    float inv = 1.0f / lrow[rr];
    int row = b * Ss + q0 + w * 16 + g * 4 + rr;
#pragma unroll
    for (int n = 0; n < 4; n++) {
      AO[(size_t)row * Dd + h * DHd + n * 16 + c] = f2b(Oa[n][rr] * inv);
    }
  }
}

// ---------------------------------------------------------------- host side
template <int BM, int BN, bool NMAJOR, typename OutT, bool RELU>
static void gemm(hipStream_t st, const ushort_t* A, const ushort_t* BT, const float* bias,
                 const float* resid, OutT* C, int M, int N, int K, int ldc) {
  int nbM = M / BM, nbN = N / BN;
  dim3 g(nbM * nbN), blk(256);
  mfma_gemm_k<BM, BN, NMAJOR, OutT, RELU><<<g, blk, 0, st>>>(A, BT, bias, resid, C, M, N, K, ldc, nbM, nbN);
}

extern "C" void kernel_launch(void* const* d_in, const int* in_sizes, int n_in,
                              void* d_out, int out_size, void* d_ws, size_t ws_size,
                              hipStream_t stream) {
  const int*   tokens    = (const int*)d_in[0];
  const float* emb       = (const float*)d_in[1];
  const float* enc_wq    = (const float*)d_in[2];
  const float* enc_wk    = (const float*)d_in[3];
  const float* enc_wv    = (const float*)d_in[4];
  const float* enc_uo_w  = (const float*)d_in[5];
  const float* enc_uo_b  = (const float*)d_in[6];
  const float* enc_ln1_g = (const float*)d_in[7];
  const float* enc_ln1_b = (const float*)d_in[8];
  const float* enc_ln2_g = (const float*)d_in[9];
  const float* enc_ln2_b = (const float*)d_in[10];
  const float* enc_ff_w1 = (const float*)d_in[11];
  const float* enc_ff_b1 = (const float*)d_in[12];
  const float* enc_ff_w2 = (const float*)d_in[13];
  const float* enc_ff_b2 = (const float*)d_in[14];
  const float* dec_sa_wq = (const float*)d_in[15];
  const float* dec_sa_wk = (const float*)d_in[16];
  const float* dec_sa_wv = (const float*)d_in[17];
  const float* dec_sa_uo_w = (const float*)d_in[18];
  const float* dec_sa_uo_b = (const float*)d_in[19];
  const float* dec_ca_wq = (const float*)d_in[20];
  const float* dec_ca_wk = (const float*)d_in[21];
  const float* dec_ca_wv = (const float*)d_in[22];
  const float* dec_ca_uo_w = (const float*)d_in[23];
  const float* dec_ca_uo_b = (const float*)d_in[24];
  const float* dec_ln1_g = (const float*)d_in[25];
  const float* dec_ln1_b = (const float*)d_in[26];
  const float* dec_ln2_g = (const float*)d_in[27];
  const float* dec_ln2_b = (const float*)d_in[28];
  const float* dec_ln3_g = (const float*)d_in[29];
  const float* dec_ln3_b = (const float*)d_in[30];
  const float* dec_ff_w1 = (const float*)d_in[31];
  const float* dec_ff_b1 = (const float*)d_in[32];
  const float* dec_ff_w2 = (const float*)d_in[33];
  const float* dec_ff_b2 = (const float*)d_in[34];
  const float* ln_enc_g  = (const float*)d_in[35];
  const float* ln_enc_b  = (const float*)d_in[36];
  const float* ln_dec_g  = (const float*)d_in[37];
  const float* ln_dec_b  = (const float*)d_in[38];
  const float* head_w    = (const float*)d_in[39];
  const float* head_b    = (const float*)d_in[40];
  float* out = (float*)d_out;

  char* ws = (char*)d_ws;
  size_t off = 0;
  auto alloc = [&](size_t bytes) {
    void* p = ws + off;
    off += (bytes + 255) & ~(size_t)255;
    return p;
  };
  ushort_t* Hb    = (ushort_t*)alloc((size_t)Tt * Dd * 2);
  ushort_t* ENCFb = (ushort_t*)alloc((size_t)Tt * Dd * 2);
  float*    X     = (float*)alloc((size_t)Tt * Dd * 4);
  float*    ENC   = (float*)alloc((size_t)Tt * Dd * 4);
  float*    QKV   = (float*)alloc((size_t)Tt * QKVW * 4);
  ushort_t* AO    = (ushort_t*)alloc((size_t)Tt * Dd * 2);
  ushort_t* Fb    = (ushort_t*)alloc((size_t)Tt * FFf * 2);
  ushort_t* BTqkv = (ushort_t*)alloc((size_t)QKVW * Dd * 2);
  ushort_t* BTuo  = (ushort_t*)alloc((size_t)Dd * Dd * 2);
  ushort_t* BTff1 = (ushort_t*)alloc((size_t)FFf * Dd * 2);
  ushort_t* BTff2 = (ushort_t*)alloc((size_t)Dd * FFf * 2);
  ushort_t* BThead = (ushort_t*)X;   // head BT reuses dead X.. region at tail

  dim3 blk(256), fblk(128);
  dim3 qkvG((QKVW * Dd + 255) / 256);
  dim3 attnG(Bb * Hh * (Ss / 32));   // 512 blocks, balanced qt order
  auto tcG = [](int R, int C) { return dim3(C / 32, R / 32); };

  embed_pe_k<<<Tt, blk, 0, stream>>>(tokens, emb, X, ENC);

  // -------- encoder --------
  for (int l = 0; l < 2; l++) {
    layernorm_k<<<Tt, blk, 0, stream>>>(ENC, enc_ln1_g + l * Dd, enc_ln1_b + l * Dd, Hb);
    qkvpack_k<<<qkvG, blk, 0, stream>>>(enc_wq + (size_t)l * Hh * Dd * DHd,
                                        enc_wk + (size_t)l * Hh * Dd * DHd,
                                        enc_wv + (size_t)l * Hh * Dd * DHd, BTqkv);
    gemm<64, 128, true, float, false>(stream, Hb, BTqkv, nullptr, nullptr, QKV, Tt, QKVW, Dd, QKVW);
    fattn_k<<<attnG, fblk, 0, stream>>>(QKV, AO);
    tcast_k<<<tcG(Dd, Dd), blk, 0, stream>>>(enc_uo_w + (size_t)l * Dd * Dd, BTuo, Dd, Dd);
    gemm<64, 64, true, float, false>(stream, AO, BTuo, enc_uo_b + l * Dd, ENC, ENC, Tt, Dd, Dd, Dd);
    layernorm_k<<<Tt, blk, 0, stream>>>(ENC, enc_ln2_g + l * Dd, enc_ln2_b + l * Dd, Hb);
    tcast_k<<<tcG(Dd, FFf), blk, 0, stream>>>(enc_ff_w1 + (size_t)l * Dd * FFf, BTff1, Dd, FFf);
    gemm<128, 128, true, ushort_t, true>(stream, Hb, BTff1, enc_ff_b1 + l * FFf, nullptr, Fb, Tt, FFf, Dd, FFf);
    tcast_k<<<tcG(FFf, Dd), blk, 0, stream>>>(enc_ff_w2 + (size_t)l * FFf * Dd, BTff2, FFf, Dd);
    gemm<64, 64, false, float, false>(stream, Fb, BTff2, enc_ff_b2 + l * Dd, ENC, ENC, Tt, Dd, FFf, Dd);
  }
  layernorm_k<<<Tt, blk, 0, stream>>>(ENC, ln_enc_g, ln_enc_b, ENCFb);

  // -------- decoder --------
  for (int l = 0; l < 2; l++) {
    layernorm_k<<<Tt, blk, 0, stream>>>(X, dec_ln1_g + l * Dd, dec_ln1_b + l * Dd, Hb);
    qkvpack_k<<<qkvG, blk, 0, stream>>>(dec_sa_wq + (size_t)l * Hh * Dd * DHd,
                                        dec_sa_wk + (size_t)l * Hh * Dd * DHd,
                                        dec_sa_wv + (size_t)l * Hh * Dd * DHd, BTqkv);
    gemm<64, 128, true, float, false>(stream, Hb, BTqkv, nullptr, nullptr, QKV, Tt, QKVW, Dd, QKVW);
    fattn_k<<<attnG, fblk, 0, stream>>>(QKV, AO);
    tcast_k<<<tcG(Dd, Dd), blk, 0, stream>>>(dec_sa_uo_w + (size_t)l * Dd * Dd, BTuo, Dd, Dd);
    gemm<64, 64, true, float, false>(stream, AO, BTuo, dec_sa_uo_b + l * Dd, X, X, Tt, Dd, Dd, Dd);
    // cross-attention: Q from LN(x), K/V from ENCFb (faithful causal mask)
    layernorm_k<<<Tt, blk, 0, stream>>>(X, dec_ln2_g + l * Dd, dec_ln2_b + l * Dd, Hb);
    qkvpack_k<<<qkvG, blk, 0, stream>>>(dec_ca_wq + (size_t)l * Hh * Dd * DHd,
                                        dec_ca_wk + (size_t)l * Hh * Dd * DHd,
                                        dec_ca_wv + (size_t)l * Hh * Dd * DHd, BTqkv);
    gemm<64, 64, true, float, false>(stream, Hb, BTqkv, nullptr, nullptr, QKV, Tt, Dd, Dd, QKVW);
    gemm<64, 128, true, float, false>(stream, ENCFb, BTqkv + (size_t)Dd * Dd, nullptr, nullptr,
                                      QKV + Dd, Tt, 2 * Dd, Dd, QKVW);
    fattn_k<<<attnG, fblk, 0, stream>>>(QKV, AO);
    tcast_k<<<tcG(Dd, Dd), blk, 0, stream>>>(dec_ca_uo_w + (size_t)l * Dd * Dd, BTuo, Dd, Dd);
    gemm<64, 64, true, float, false>(stream, AO, BTuo, dec_ca_uo_b + l * Dd, X, X, Tt, Dd, Dd, Dd);
    // ffn
    layernorm_k<<<Tt, blk, 0, stream>>>(X, dec_ln3_g + l * Dd, dec_ln3_b + l * Dd, Hb);
    tcast_k<<<tcG(Dd, FFf), blk, 0, stream>>>(dec_ff_w1 + (size_t)l * Dd * FFf, BTff1, Dd, FFf);
    gemm<128, 128, true, ushort_t, true>(stream, Hb, BTff1, dec_ff_b1 + l * FFf, nullptr, Fb, Tt, FFf, Dd, FFf);
    tcast_k<<<tcG(FFf, Dd), blk, 0, stream>>>(dec_ff_w2 + (size_t)l * FFf * Dd, BTff2, FFf, Dd);
    gemm<64, 64, false, float, false>(stream, Fb, BTff2, dec_ff_b2 + l * Dd, X, X, Tt, Dd, FFf, Dd);
  }
  layernorm_k<<<Tt, blk, 0, stream>>>(X, ln_dec_g, ln_dec_b, Hb);  // X dead after this

  tcast_k<<<tcG(Dd, Vv), blk, 0, stream>>>(head_w, BThead, Dd, Vv);
  gemm<128, 128, true, float, false>(stream, Hb, BThead, head_b, nullptr, out, Tt, Vv, Dd, Vv);
}